// Round 21
// baseline (261.594 us; speedup 1.0000x reference)
//
#include <hip/hip_runtime.h>
#include <math.h>

#define BB 2
#define SS 2048
#define DD 256
#define HH 8
#define DKK 32
#define DVV 32
#define DFF 512
#define NL 2

// attention tiling
#define KSTR 40
#define VSTR 72
#define NSPLIT 4
#define SCHUNK (SS / NSPLIT)   // 512 keys per block

// gemm tiling
#define XSTR 264     // 16-row X tile stride (ushort)
#define HSTR 520     // 16-row H tile stride (ushort)
#define YSTR 260     // Y tile stride (float)

typedef __attribute__((ext_vector_type(8))) short short8;
typedef __attribute__((ext_vector_type(4))) float f32x4;
typedef __attribute__((ext_vector_type(16))) float f32x16;

static __device__ __forceinline__ float ln_eps2() { return 1.4210854715202004e-14f; }

static __device__ __forceinline__ ushort f2bf(float f) {
    union { float f; unsigned u; } c; c.f = f;
    unsigned r = c.u + 0x7FFFu + ((c.u >> 16) & 1u);   // RNE
    return (ushort)(r >> 16);
}
static __device__ __forceinline__ float bf2f(ushort h) {
    union { unsigned u; float f; } c; c.u = ((unsigned)h) << 16;
    return c.f;
}
static __device__ __forceinline__ unsigned cvtpk_bf16(float a, float b) {
    unsigned r;
    asm volatile("v_cvt_pk_bf16_f32 %0, %1, %2" : "=v"(r) : "v"(a), "v"(b));
    return r;   // lo = bf16(a), hi = bf16(b)
}

// ---------------- Kernel 0a: W1/W2 convert+transpose (proven) ----------------
__global__ __launch_bounds__(256) void wtrans_kernel(
    const float* __restrict__ W1, const float* __restrict__ W2,
    ushort* __restrict__ w1t_hi, ushort* __restrict__ w1t_lo,
    ushort* __restrict__ w2t_hi, ushort* __restrict__ w2t_lo)
{
    __shared__ ushort Th[64][72];
    __shared__ ushort Tl[64][72];
    const int bid = blockIdx.x;              // 0..127
    const float* src; ushort *dh, *dl; int R, C, tile;
    if (bid < 64) {                          // W1
        const int l = bid >> 5; tile = bid & 31;
        src = W1 + (size_t)l * DD * DFF;
        dh = w1t_hi + (size_t)l * DFF * DD; dl = w1t_lo + (size_t)l * DFF * DD;
        R = DD; C = DFF;
    } else {                                 // W2
        const int l = (bid - 64) >> 5; tile = (bid - 64) & 31;
        src = W2 + (size_t)l * DFF * DD;
        dh = w2t_hi + (size_t)l * DD * DFF; dl = w2t_lo + (size_t)l * DD * DFF;
        R = DFF; C = DD;
    }
    const int tilesC = C / 64;
    const int br = (tile / tilesC) * 64, bc = (tile % tilesC) * 64;
    const int tid = threadIdx.x;
#pragma unroll
    for (int i = 0; i < 16; ++i) {
        const int p = i * 256 + tid;
        const int r = p >> 6, c = p & 63;
        const float f = src[(size_t)(br + r) * C + bc + c];
        const ushort h = f2bf(f);
        Th[c][r] = h; Tl[c][r] = f2bf(f - bf2f(h));
    }
    __syncthreads();
#pragma unroll
    for (int i = 0; i < 16; ++i) {
        const int p = i * 256 + tid;
        const int r = p >> 6, c = p & 63;
        dh[(size_t)(bc + r) * R + br + c] = Th[r][c];
        dl[(size_t)(bc + r) * R + br + c] = Tl[r][c];
    }
}

// ---------------- Kernel 0b: Wo -> woT hi/lo [l][256][256] (proven) ----------------
__global__ __launch_bounds__(256) void wotrans_kernel(
    const float* __restrict__ Wo,
    ushort* __restrict__ wh, ushort* __restrict__ wl)
{
    __shared__ float T[64][65];
    const int l = blockIdx.x >> 4, tile = blockIdx.x & 15;
    const int tr = (tile >> 2) * 64;
    const int tc = (tile & 3) * 64;
    const float* src = Wo + (size_t)l * DD * DD;
    ushort* dh = wh + (size_t)l * DD * DD;
    ushort* dl = wl + (size_t)l * DD * DD;
    const int tid = threadIdx.x;
#pragma unroll
    for (int i = 0; i < 16; ++i) {
        const int p = i * 256 + tid;
        const int r = p >> 6, c = p & 63;
        T[r][c] = src[(size_t)(tr + r) * DD + tc + c];
    }
    __syncthreads();
#pragma unroll
    for (int i = 0; i < 16; ++i) {
        const int p = i * 256 + tid;
        const int r = p >> 6, c = p & 63;
        const float f = T[c][r];
        const size_t off = (size_t)(tc + r) * DD + tr + c;
        const ushort h = f2bf(f);
        dh[off] = h;
        dl[off] = f2bf(f - bf2f(h));
    }
}

// ---------------- Kernel 0c: Wq/Wk/Wv -> wqkvT hi/lo [l][768][256] ----------------
// K rows (src==1) pre-scaled by log2(e) so attention logits are in log2 units.
__global__ __launch_bounds__(256) void wqkv_trans_kernel(
    const float* __restrict__ Wq, const float* __restrict__ Wk,
    const float* __restrict__ Wv,
    ushort* __restrict__ qkvT_hi, ushort* __restrict__ qkvT_lo)
{
    __shared__ float T[DKK][DD + 1];
    const int bid = blockIdx.x;              // l*24 + src*8 + h
    const int l = bid / 24, rem = bid % 24, src = rem >> 3, h = rem & 7;
    const float* W = (src == 0 ? Wq : src == 1 ? Wk : Wv)
                     + ((size_t)l * HH + h) * DD * DKK;
    ushort* dh = qkvT_hi + ((size_t)l * 768 + src * 256 + h * 32) * DD;
    ushort* dl = qkvT_lo + ((size_t)l * 768 + src * 256 + h * 32) * DD;
    const float scl = (src == 1) ? 1.4426950408889634f : 1.0f;
    const int tid = threadIdx.x;
#pragma unroll
    for (int i = 0; i < 32; ++i) {           // W[d][dk] -> T[dk][d]
        const int p = i * 256 + tid;
        T[p & 31][p >> 5] = W[p];
    }
    __syncthreads();
#pragma unroll
    for (int i = 0; i < 32; ++i) {
        const int p = i * 256 + tid;
        const int dk = p >> 8, d = p & 255;
        const float f = T[dk][d] * scl;
        const ushort hh = f2bf(f);
        dh[dk * DD + d] = hh;
        dl[dk * DD + d] = f2bf(f - bf2f(hh));
    }
}

// ---------------- Kernel 1: QKV via MFMA, 2-way column split (round-18 proven) ----------------
// grid = (B*S/16)*2; V written directly transposed: vt[bh][dv][s].
__global__ __launch_bounds__(256) void qkv_mfma_kernel(
    const float* __restrict__ xin,
    const ushort* __restrict__ wth, const ushort* __restrict__ wtl,
    float* __restrict__ q, ushort* __restrict__ khi, ushort* __restrict__ klo,
    ushort* __restrict__ vt)
{
    __shared__ __align__(16) ushort Xh[16 * XSTR];
    __shared__ __align__(16) ushort Xl[16 * XSTR];

    const int tid = threadIdx.x, wave = tid >> 6, lane = tid & 63;
    const int c16 = lane & 15, g = lane >> 4;
    const int row0 = (blockIdx.x >> 1) * 16;
    const int half = blockIdx.x & 1;

#pragma unroll
    for (int i = 0; i < 16; ++i) {
        const int p = i * 256 + tid;
        const int r = p >> 8, c = p & 255;
        const float f = xin[(size_t)(row0 + r) * DD + c];
        const ushort h = f2bf(f);
        Xh[r * XSTR + c] = h;
        Xl[r * XSTR + c] = f2bf(f - bf2f(h));
    }
    __syncthreads();

    short8 xf_h[8], xf_l[8];
#pragma unroll
    for (int kk = 0; kk < 8; ++kk) {
        xf_h[kk] = *(const short8*)&Xh[c16 * XSTR + kk * 32 + g * 8];
        xf_l[kk] = *(const short8*)&Xl[c16 * XSTR + kk * 32 + g * 8];
    }

    const int b = row0 / SS, s0 = row0 % SS;
    const int wbase = half * 384 + wave * 96;
#pragma unroll 2
    for (int t = 0; t < 6; ++t) {
        const int ncol = wbase + t * 16 + c16;
        const ushort* wh = wth + (size_t)ncol * DD;
        const ushort* wl = wtl + (size_t)ncol * DD;
        f32x4 acc = (f32x4)(0.f);
#pragma unroll
        for (int kk = 0; kk < 8; ++kk) {
            const short8 bh = *(const short8*)(wh + kk * 32 + g * 8);
            const short8 bl = *(const short8*)(wl + kk * 32 + g * 8);
            acc = __builtin_amdgcn_mfma_f32_16x16x32_bf16(xf_h[kk], bh, acc, 0, 0, 0);
            acc = __builtin_amdgcn_mfma_f32_16x16x32_bf16(xf_l[kk], bh, acc, 0, 0, 0);
            acc = __builtin_amdgcn_mfma_f32_16x16x32_bf16(xf_h[kk], bl, acc, 0, 0, 0);
        }
        const int src = ncol >> 8, h = (ncol >> 5) & 7, dk = ncol & 31;
        const size_t base = ((size_t)(b * HH + h) * SS + s0) * DKK + dk;
#pragma unroll
        for (int r = 0; r < 4; ++r) {
            if (src == 0) {
                q[base + (size_t)(4 * g + r) * DKK] = acc[r];
            } else if (src == 1) {
                const size_t off = base + (size_t)(4 * g + r) * DKK;
                const ushort hh = f2bf(acc[r]);
                khi[off] = hh;
                klo[off] = f2bf(acc[r] - bf2f(hh));
            } else {
                vt[((size_t)(b * HH + h) * DVV + dk) * SS + s0 + 4 * g + r] = f2bf(acc[r]);
            }
        }
    }
}

// ---------------- Kernel 2: swapped-operand 32x32 flash attention, split-K=4 ----------------
// exp2-based softmax (K pre-scaled by log2e) + defer-max (THR=8).
__global__ __launch_bounds__(256) void attn_mfma_kernel(
    const float* __restrict__ q, const ushort* __restrict__ khi,
    const ushort* __restrict__ klo, const ushort* __restrict__ vt,
    float* __restrict__ opart, float* __restrict__ ml)
{
    __shared__ ushort KhS[64 * KSTR];        // 5120 B
    __shared__ ushort KlS[64 * KSTR];        // 5120 B
    __shared__ ushort VtS[32 * VSTR];        // 4608 B

    const int tid  = threadIdx.x;
    const int wave = tid >> 6;
    const int lane = tid & 63;
    const int c32  = lane & 31;
    const int hi   = lane >> 5;

    const int nqb = SS / 128;                // 16
    const int bh  = blockIdx.x / (nqb * NSPLIT);
    const int rem = blockIdx.x % (nqb * NSPLIT);
    const int qb  = rem / NSPLIT;
    const int sp  = rem % NSPLIT;
    const int qrow = qb * 128 + wave * 32 + c32;

    const float*  qp  = q   + (size_t)bh * SS * DKK;
    const ushort* khp = khi + (size_t)bh * SS * DKK;
    const ushort* klp = klo + (size_t)bh * SS * DKK;
    const ushort* vtp = vt  + (size_t)bh * DVV * SS;

    short8 qh0, ql0, qh1, ql1;
    {
        const float* qr = qp + (size_t)qrow * DKK + hi * 8;
#pragma unroll
        for (int j = 0; j < 8; ++j) {
            const ushort h = f2bf(qr[j]);
            qh0[j] = (short)h; ql0[j] = (short)f2bf(qr[j] - bf2f(h));
        }
#pragma unroll
        for (int j = 0; j < 8; ++j) {
            const float f = qr[16 + j];
            const ushort h = f2bf(f);
            qh1[j] = (short)h; ql1[j] = (short)f2bf(f - bf2f(h));
        }
    }

    float m = -1e30f, l = 0.f;
    f32x16 oacc = (f32x16)(0.f);
    const f32x16 zero16 = (f32x16)(0.f);

    for (int kt = sp * SCHUNK; kt < (sp + 1) * SCHUNK; kt += 64) {
#pragma unroll
        for (int i = 0; i < 2; ++i) {
            const int p = i * 256 + tid;
            const int row = p >> 3;
            const int col4 = (p & 7) * 4;
            const uint2 h8 = *(const uint2*)(khp + (size_t)(kt + row) * DKK + col4);
            const uint2 l8 = *(const uint2*)(klp + (size_t)(kt + row) * DKK + col4);
            *(uint2*)&KhS[row * KSTR + col4] = h8;
            *(uint2*)&KlS[row * KSTR + col4] = l8;
        }
#pragma unroll
        for (int i = 0; i < 2; ++i) {
            const int p = i * 256 + tid;
            const int dv = p >> 4;
            const int s8 = (p & 15) * 4;
            const uint2 v8 = *(const uint2*)(vtp + (size_t)dv * SS + kt + s8);
            *(uint2*)&VtS[dv * VSTR + s8] = v8;
        }
        __syncthreads();

        f32x16 s0, s1;
        {
            const int rb0 = c32 * KSTR + hi * 8;
            const short8 kh0 = *(const short8*)&KhS[rb0];
            const short8 kl0 = *(const short8*)&KlS[rb0];
            const short8 kh1 = *(const short8*)&KhS[rb0 + 16];
            const short8 kl1 = *(const short8*)&KlS[rb0 + 16];
            f32x16 s = __builtin_amdgcn_mfma_f32_32x32x16_bf16(kh0, ql0, zero16, 0, 0, 0);
            s = __builtin_amdgcn_mfma_f32_32x32x16_bf16(kl0, qh0, s, 0, 0, 0);
            s = __builtin_amdgcn_mfma_f32_32x32x16_bf16(kh0, qh0, s, 0, 0, 0);
            s = __builtin_amdgcn_mfma_f32_32x32x16_bf16(kh1, ql1, s, 0, 0, 0);
            s = __builtin_amdgcn_mfma_f32_32x32x16_bf16(kl1, qh1, s, 0, 0, 0);
            s0 = __builtin_amdgcn_mfma_f32_32x32x16_bf16(kh1, qh1, s, 0, 0, 0);
        }
        {
            const int rb1 = (32 + c32) * KSTR + hi * 8;
            const short8 kh0 = *(const short8*)&KhS[rb1];
            const short8 kl0 = *(const short8*)&KlS[rb1];
            const short8 kh1 = *(const short8*)&KhS[rb1 + 16];
            const short8 kl1 = *(const short8*)&KlS[rb1 + 16];
            f32x16 s = __builtin_amdgcn_mfma_f32_32x32x16_bf16(kh0, ql0, zero16, 0, 0, 0);
            s = __builtin_amdgcn_mfma_f32_32x32x16_bf16(kl0, qh0, s, 0, 0, 0);
            s = __builtin_amdgcn_mfma_f32_32x32x16_bf16(kh0, qh0, s, 0, 0, 0);
            s = __builtin_amdgcn_mfma_f32_32x32x16_bf16(kh1, ql1, s, 0, 0, 0);
            s = __builtin_amdgcn_mfma_f32_32x32x16_bf16(kl1, qh1, s, 0, 0, 0);
            s1 = __builtin_amdgcn_mfma_f32_32x32x16_bf16(kh1, qh1, s, 0, 0, 0);
        }

        // ---- online softmax (log2-units) with defer-max ----
        float tm = s0[0];
#pragma unroll
        for (int j = 1; j < 16; ++j) tm = fmaxf(tm, s0[j]);
#pragma unroll
        for (int j = 0; j < 16; ++j) tm = fmaxf(tm, s1[j]);
        tm = fmaxf(tm, __shfl_xor(tm, 32));
        if (!__all(tm <= m + 8.0f)) {
            const float nm = fmaxf(m, tm);
            const float scale = exp2f(m - nm);
            l *= scale;
#pragma unroll
            for (int j = 0; j < 16; ++j) oacc[j] *= scale;
            m = nm;
        }
        float psum = 0.f;
#pragma unroll
        for (int j = 0; j < 16; ++j) { const float p = exp2f(s0[j] - m); s0[j] = p; psum += p; }
#pragma unroll
        for (int j = 0; j < 16; ++j) { const float p = exp2f(s1[j] - m); s1[j] = p; psum += p; }
        psum += __shfl_xor(psum, 32);
        l += psum;

        unsigned w0 = cvtpk_bf16(s0[0],  s0[1]);
        unsigned w1 = cvtpk_bf16(s0[2],  s0[3]);
        unsigned w2 = cvtpk_bf16(s0[4],  s0[5]);
        unsigned w3 = cvtpk_bf16(s0[6],  s0[7]);
        unsigned w4 = cvtpk_bf16(s0[8],  s0[9]);
        unsigned w5 = cvtpk_bf16(s0[10], s0[11]);
        unsigned w6 = cvtpk_bf16(s0[12], s0[13]);
        unsigned w7 = cvtpk_bf16(s0[14], s0[15]);
        unsigned u0 = cvtpk_bf16(s1[0],  s1[1]);
        unsigned u1 = cvtpk_bf16(s1[2],  s1[3]);
        unsigned u2 = cvtpk_bf16(s1[4],  s1[5]);
        unsigned u3 = cvtpk_bf16(s1[6],  s1[7]);
        unsigned u4 = cvtpk_bf16(s1[8],  s1[9]);
        unsigned u5 = cvtpk_bf16(s1[10], s1[11]);
        unsigned u6 = cvtpk_bf16(s1[12], s1[13]);
        unsigned u7 = cvtpk_bf16(s1[14], s1[15]);

        const unsigned x0 = __shfl_xor(hi ? w0 : w2, 32);
        const unsigned x1 = __shfl_xor(hi ? w1 : w3, 32);
        const unsigned x2 = __shfl_xor(hi ? w4 : w6, 32);
        const unsigned x3 = __shfl_xor(hi ? w5 : w7, 32);
        const unsigned y0 = __shfl_xor(hi ? u0 : u2, 32);
        const unsigned y1 = __shfl_xor(hi ? u1 : u3, 32);
        const unsigned y2 = __shfl_xor(hi ? u4 : u6, 32);
        const unsigned y3 = __shfl_xor(hi ? u5 : u7, 32);

        union { unsigned u[4]; short8 s8; } pa, pb, pc, pd;
        if (hi == 0) {
            pa.u[0] = w0; pa.u[1] = w1; pa.u[2] = x0; pa.u[3] = x1;   // keys 0..7
            pb.u[0] = w4; pb.u[1] = w5; pb.u[2] = x2; pb.u[3] = x3;   // keys 16..23
            pc.u[0] = u0; pc.u[1] = u1; pc.u[2] = y0; pc.u[3] = y1;   // keys 32..39
            pd.u[0] = u4; pd.u[1] = u5; pd.u[2] = y2; pd.u[3] = y3;   // keys 48..55
        } else {
            pa.u[0] = x0; pa.u[1] = x1; pa.u[2] = w2; pa.u[3] = w3;   // keys 8..15
            pb.u[0] = x2; pb.u[1] = x3; pb.u[2] = w6; pb.u[3] = w7;   // keys 24..31
            pc.u[0] = y0; pc.u[1] = y1; pc.u[2] = u2; pc.u[3] = u3;   // keys 40..47
            pd.u[0] = y2; pd.u[1] = y3; pd.u[2] = u6; pd.u[3] = u7;   // keys 56..63
        }

        {
            const int vb2 = c32 * VSTR + hi * 8;
            const short8 v0 = *(const short8*)&VtS[vb2];
            const short8 v1 = *(const short8*)&VtS[vb2 + 16];
            const short8 v2 = *(const short8*)&VtS[vb2 + 32];
            const short8 v3 = *(const short8*)&VtS[vb2 + 48];
            oacc = __builtin_amdgcn_mfma_f32_32x32x16_bf16(v0, pa.s8, oacc, 0, 0, 0);
            oacc = __builtin_amdgcn_mfma_f32_32x32x16_bf16(v1, pb.s8, oacc, 0, 0, 0);
            oacc = __builtin_amdgcn_mfma_f32_32x32x16_bf16(v2, pc.s8, oacc, 0, 0, 0);
            oacc = __builtin_amdgcn_mfma_f32_32x32x16_bf16(v3, pd.s8, oacc, 0, 0, 0);
        }
        __syncthreads();
    }

    const size_t pbase = (size_t)(sp * BB * HH + bh) * SS;
    float* op = opart + (pbase + qrow) * DVV;
#pragma unroll
    for (int q4 = 0; q4 < 4; ++q4) {
        f32x4 v;
        v[0] = oacc[4 * q4 + 0]; v[1] = oacc[4 * q4 + 1];
        v[2] = oacc[4 * q4 + 2]; v[3] = oacc[4 * q4 + 3];
        *(f32x4*)(op + 8 * q4 + 4 * hi) = v;
    }
    if (hi == 0) {
        ml[(pbase + qrow) * 2]     = m;
        ml[(pbase + qrow) * 2 + 1] = l;
    }
}

// ---------------- Kernel 2b: split-K merge (log2-unit m) -> o concat layout ----------------
__global__ __launch_bounds__(256) void attn_merge_kernel(
    const float* __restrict__ opart, const float* __restrict__ ml,
    float* __restrict__ o)
{
    const int nch = SS / 128;                // 16
    const int bh = blockIdx.x / nch;
    const int chunk = blockIdx.x % nch;
    const int q0 = chunk * 128;
    const int b = bh >> 3, h = bh & 7;
    const int tid = threadIdx.x;

#pragma unroll
    for (int i = 0; i < 16; ++i) {
        const int p = i * 256 + tid;
        const int ql = p >> 5, dv = p & 31;
        const int qr = q0 + ql;
        float ms[NSPLIT], ls[NSPLIT];
#pragma unroll
        for (int s = 0; s < NSPLIT; ++s) {
            const size_t pb = (size_t)(s * BB * HH + bh) * SS + qr;
            ms[s] = ml[pb * 2];
            ls[s] = ml[pb * 2 + 1];
        }
        float M = ms[0];
#pragma unroll
        for (int s = 1; s < NSPLIT; ++s) M = fmaxf(M, ms[s]);
        float L = 0.f, acc = 0.f;
#pragma unroll
        for (int s = 0; s < NSPLIT; ++s) {
            const float w = exp2f(ms[s] - M);
            L += w * ls[s];
            acc += w * opart[((size_t)(s * BB * HH + bh) * SS + qr) * DVV + dv];
        }
        o[(size_t)(b * SS + qr) * (HH * DVV) + h * DVV + dv] = acc / L;
    }
}

// ---------------- Kernel 3: proj via MFMA (proven) ----------------
__global__ __launch_bounds__(256) void proj_mfma_kernel(
    const float* __restrict__ conc, const float* __restrict__ xres,
    const ushort* __restrict__ wth, const ushort* __restrict__ wtl,
    const float* __restrict__ gamma, const float* __restrict__ beta,
    float* __restrict__ xout)
{
    __shared__ __align__(16) ushort Xh[16 * XSTR];
    __shared__ __align__(16) ushort Xl[16 * XSTR];
    __shared__ float Y[16 * YSTR];

    const int tid = threadIdx.x, wave = tid >> 6, lane = tid & 63;
    const int c16 = lane & 15, g = lane >> 4;
    const int row0 = blockIdx.x * 16;

#pragma unroll
    for (int i = 0; i < 16; ++i) {
        const int p = i * 256 + tid;
        const int r = p >> 8, c = p & 255;
        const float f = conc[(size_t)(row0 + r) * DD + c];
        const ushort h = f2bf(f);
        Xh[r * XSTR + c] = h;
        Xl[r * XSTR + c] = f2bf(f - bf2f(h));
    }
    __syncthreads();

    short8 xf_h[8], xf_l[8];
#pragma unroll
    for (int kk = 0; kk < 8; ++kk) {
        xf_h[kk] = *(const short8*)&Xh[c16 * XSTR + kk * 32 + g * 8];
        xf_l[kk] = *(const short8*)&Xl[c16 * XSTR + kk * 32 + g * 8];
    }

    const int wbase = wave * 64;
#pragma unroll 2
    for (int t = 0; t < 4; ++t) {
        const int ncol = wbase + t * 16 + c16;
        const ushort* wh = wth + (size_t)ncol * DD;
        const ushort* wl = wtl + (size_t)ncol * DD;
        f32x4 acc = (f32x4)(0.f);
#pragma unroll
        for (int kk = 0; kk < 8; ++kk) {
            const short8 bh = *(const short8*)(wh + kk * 32 + g * 8);
            const short8 bl = *(const short8*)(wl + kk * 32 + g * 8);
            acc = __builtin_amdgcn_mfma_f32_16x16x32_bf16(xf_h[kk], bh, acc, 0, 0, 0);
            acc = __builtin_amdgcn_mfma_f32_16x16x32_bf16(xf_l[kk], bh, acc, 0, 0, 0);
            acc = __builtin_amdgcn_mfma_f32_16x16x32_bf16(xf_h[kk], bl, acc, 0, 0, 0);
        }
#pragma unroll
        for (int r = 0; r < 4; ++r)
            Y[(4 * g + r) * YSTR + ncol] = acc[r];
    }
    __syncthreads();

    const float g0 = gamma[0], b0 = beta[0];
#pragma unroll
    for (int rr = 0; rr < 4; ++rr) {
        const int row = wave * 4 + rr;
        float v[4];
        float sum = 0.f;
#pragma unroll
        for (int j = 0; j < 4; ++j) {
            const int c = lane + 64 * j;
            v[j] = Y[row * YSTR + c] + xres[(size_t)(row0 + row) * DD + c];
            sum += v[j];
        }
#pragma unroll
        for (int m = 32; m >= 1; m >>= 1) sum += __shfl_xor(sum, m);
        const float mean = sum * (1.0f / DD);
        float var = 0.f;
#pragma unroll
        for (int j = 0; j < 4; ++j) { v[j] -= mean; var += v[j] * v[j]; }
#pragma unroll
        for (int m = 32; m >= 1; m >>= 1) var += __shfl_xor(var, m);
        var *= (1.0f / DD);
        const float rstd = 1.0f / sqrtf(var + ln_eps2());
#pragma unroll
        for (int j = 0; j < 4; ++j)
            xout[(size_t)(row0 + row) * DD + lane + 64 * j] = v[j] * rstd * g0 + b0;
    }
}

// ---------------- Kernel 4: FFN via MFMA + residual + LN (proven) ----------------
__global__ __launch_bounds__(256) void ffn_mfma_kernel(
    const float* __restrict__ xin,
    const ushort* __restrict__ w1th, const ushort* __restrict__ w1tl,
    const ushort* __restrict__ w2th, const ushort* __restrict__ w2tl,
    const float* __restrict__ b1, const float* __restrict__ b2,
    const float* __restrict__ gamma, const float* __restrict__ beta,
    float* __restrict__ xout)
{
    __shared__ __align__(16) char smem[(2 * 16 * XSTR + 2 * 16 * HSTR) * 2];
    ushort* Xh = (ushort*)smem;
    ushort* Xl = Xh + 16 * XSTR;
    ushort* Hh = Xl + 16 * XSTR;
    ushort* Hl = Hh + 16 * HSTR;
    float*  Y  = (float*)smem;

    const int tid  = threadIdx.x;
    const int wave = tid >> 6;
    const int lane = tid & 63;
    const int c16  = lane & 15;
    const int g    = lane >> 4;
    const int row0 = blockIdx.x * 16;

#pragma unroll
    for (int i = 0; i < 16; ++i) {
        const int p = i * 256 + tid;
        const int r = p >> 8, c = p & 255;
        const float f = xin[(size_t)(row0 + r) * DD + c];
        const ushort h = f2bf(f);
        Xh[r * XSTR + c] = h;
        Xl[r * XSTR + c] = f2bf(f - bf2f(h));
    }
    __syncthreads();

    short8 xf_h[8], xf_l[8];
#pragma unroll
    for (int kk = 0; kk < 8; ++kk) {
        xf_h[kk] = *(const short8*)&Xh[c16 * XSTR + kk * 32 + g * 8];
        xf_l[kk] = *(const short8*)&Xl[c16 * XSTR + kk * 32 + g * 8];
    }

    const int wbase = wave * 128;
#pragma unroll 2
    for (int t = 0; t < 8; ++t) {
        const int ncol = wbase + t * 16 + c16;
        const ushort* wh = w1th + (size_t)ncol * DD;
        const ushort* wl = w1tl + (size_t)ncol * DD;
        f32x4 acc = (f32x4)(0.f);
#pragma unroll
        for (int kk = 0; kk < 8; ++kk) {
            const short8 bh = *(const short8*)(wh + kk * 32 + g * 8);
            const short8 bl = *(const short8*)(wl + kk * 32 + g * 8);
            acc = __builtin_amdgcn_mfma_f32_16x16x32_bf16(xf_h[kk], bh, acc, 0, 0, 0);
            acc = __builtin_amdgcn_mfma_f32_16x16x32_bf16(xf_l[kk], bh, acc, 0, 0, 0);
            acc = __builtin_amdgcn_mfma_f32_16x16x32_bf16(xf_h[kk], bl, acc, 0, 0, 0);
        }
        const float bias = b1[ncol];
#pragma unroll
        for (int r = 0; r < 4; ++r) {
            const int mm = 4 * g + r;
            const float hv = fmaxf(acc[r] + bias, 0.f);
            const ushort hh = f2bf(hv);
            Hh[mm * HSTR + ncol] = hh;
            Hl[mm * HSTR + ncol] = f2bf(hv - bf2f(hh));
        }
    }
    __syncthreads();

    const int obase = wave * 64;
    f32x4 acc2[4];
#pragma unroll
    for (int t = 0; t < 4; ++t) acc2[t] = (f32x4)(0.f);
#pragma unroll 2
    for (int kk = 0; kk < 16; ++kk) {
        const short8 ah = *(const short8*)&Hh[c16 * HSTR + kk * 32 + g * 8];
        const short8 al = *(const short8*)&Hl[c16 * HSTR + kk * 32 + g * 8];
#pragma unroll
        for (int t = 0; t < 4; ++t) {
            const int ncol = obase + t * 16 + c16;
            const short8 bh = *(const short8*)(w2th + (size_t)ncol * DFF + kk * 32 + g * 8);
            const short8 bl = *(const short8*)(w2tl + (size_t)ncol * DFF + kk * 32 + g * 8);
            acc2[t] = __builtin_amdgcn_mfma_f32_16x16x32_bf16(ah, bh, acc2[t], 0, 0, 0);
            acc2[t] = __builtin_amdgcn_mfma_f32_16x16x32_bf16(al, bh, acc2[t], 0, 0, 0);
            acc2[t] = __builtin_amdgcn_mfma_f32_16x16x32_bf16(ah, bl, acc2[t], 0, 0, 0);
        }
    }

#pragma unroll
    for (int t = 0; t < 4; ++t) {
        const int ncol = obase + t * 16 + c16;
#pragma unroll
        for (int r = 0; r < 4; ++r)
            Y[(4 * g + r) * YSTR + ncol] = acc2[t][r];
    }
    __syncthreads();

    const float g0 = gamma[0], b0 = beta[0];
#pragma unroll
    for (int rr = 0; rr < 4; ++rr) {
        const int row = wave * 4 + rr;
        float v[4];
        float sum = 0.f;
#pragma unroll
        for (int j = 0; j < 4; ++j) {
            const int c = lane + 64 * j;
            v[j] = Y[row * YSTR + c] + b2[c] + xin[(size_t)(row0 + row) * DD + c];
            sum += v[j];
        }
#pragma unroll
        for (int m = 32; m >= 1; m >>= 1) sum += __shfl_xor(sum, m);
        const float mean = sum * (1.0f / DD);
        float var = 0.f;
#pragma unroll
        for (int j = 0; j < 4; ++j) { v[j] -= mean; var += v[j] * v[j]; }
#pragma unroll
        for (int m = 32; m >= 1; m >>= 1) var += __shfl_xor(var, m);
        var *= (1.0f / DD);
        const float rstd = 1.0f / sqrtf(var + ln_eps2());
#pragma unroll
        for (int j = 0; j < 4; ++j)
            xout[(size_t)(row0 + row) * DD + lane + 64 * j] = v[j] * rstd * g0 + b0;
    }
}

// ---------------- host launch ----------------
extern "C" void kernel_launch(void* const* d_in, const int* in_sizes, int n_in,
                              void* d_out, int out_size, void* d_ws, size_t ws_size,
                              hipStream_t stream) {
    const float* x     = (const float*)d_in[0];
    const float* Wq    = (const float*)d_in[1];
    const float* Wk    = (const float*)d_in[2];
    const float* Wv    = (const float*)d_in[3];
    const float* Wo    = (const float*)d_in[4];
    const float* W1    = (const float*)d_in[5];
    const float* b1    = (const float*)d_in[6];
    const float* W2    = (const float*)d_in[7];
    const float* b2    = (const float*)d_in[8];
    const float* gamma = (const float*)d_in[9];
    const float* beta  = (const float*)d_in[10];
    float* out = (float*)d_out;

    const size_t NTOK = (size_t)BB * SS * DD;       // 1,048,576
    const size_t WFF  = (size_t)NL * DFF * DD;      // 262,144
    const size_t WOO  = (size_t)NL * DD * DD;       // 131,072
    const size_t WQKV = (size_t)NL * 768 * DD;      // 393,216
    float*  q    = (float*)d_ws;
    ushort* khi  = (ushort*)(q + NTOK);
    ushort* klo  = khi + NTOK;
    ushort* vt   = klo + NTOK;
    float*  o    = (float*)(vt + NTOK);
    float*  xa   = o + NTOK;
    float*  xb   = xa + NTOK;
    ushort* w1th = (ushort*)(xb + NTOK);
    ushort* w1tl = w1th + WFF;
    ushort* w2th = w1tl + WFF;
    ushort* w2tl = w2th + WFF;
    ushort* woth = w2tl + WFF;
    ushort* wotl = woth + WOO;
    ushort* wqth = wotl + WOO;
    ushort* wqtl = wqth + WQKV;
    float*  opart = (float*)(wqtl + WQKV);          // NSPLIT*B*H*S*DVV f32 = 16 MB
    float*  ml    = opart + (size_t)NSPLIT * BB * HH * SS * DVV;  // 1 MB

    wtrans_kernel<<<128, 256, 0, stream>>>(W1, W2, w1th, w1tl, w2th, w2tl);
    wotrans_kernel<<<NL * 16, 256, 0, stream>>>(Wo, woth, wotl);
    wqkv_trans_kernel<<<48, 256, 0, stream>>>(Wq, Wk, Wv, wqth, wqtl);

    const float* cur = x;
    for (int l = 0; l < NL; ++l) {
        qkv_mfma_kernel<<<2 * BB * SS / 16, 256, 0, stream>>>(
            cur, wqth + (size_t)l * 768 * DD, wqtl + (size_t)l * 768 * DD,
            q, khi, klo, vt);
        attn_mfma_kernel<<<BB * HH * (SS / 128) * NSPLIT, 256, 0, stream>>>(
            q, khi, klo, vt, opart, ml);
        attn_merge_kernel<<<BB * HH * (SS / 128), 256, 0, stream>>>(opart, ml, o);
        proj_mfma_kernel<<<BB * SS / 16, 256, 0, stream>>>(
            o, cur, woth + (size_t)l * DD * DD, wotl + (size_t)l * DD * DD,
            gamma + 2 * l, beta + 2 * l, xa);
        float* nxt = (l == NL - 1) ? out : xb;
        ffn_mfma_kernel<<<BB * SS / 16, 256, 0, stream>>>(
            xa, w1th + (size_t)l * DFF * DD, w1tl + (size_t)l * DFF * DD,
            w2th + (size_t)l * DD * DFF, w2tl + (size_t)l * DD * DFF,
            b1 + (size_t)l * DFF, b2 + (size_t)l * DD,
            gamma + 2 * l + 1, beta + 2 * l + 1, nxt);
        cur = nxt;
    }
}

// Round 22
// 244.874 us; speedup vs baseline: 1.0683x; 1.0683x over previous
//
#include <hip/hip_runtime.h>
#include <math.h>

#define BB 2
#define SS 2048
#define DD 256
#define HH 8
#define DKK 32
#define DVV 32
#define DFF 512
#define NL 2

// attention tiling
#define KSTR 40
#define VSTR 72
#define NSPLIT 4
#define SCHUNK (SS / NSPLIT)   // 512 keys per block

// gemm tiling
#define XSTR 264     // 16-row X tile stride (ushort)
#define HSTR 520     // 16-row H tile stride (ushort)
#define YSTR 260     // Y tile stride (float)

typedef __attribute__((ext_vector_type(8))) short short8;
typedef __attribute__((ext_vector_type(4))) float f32x4;
typedef __attribute__((ext_vector_type(16))) float f32x16;

static __device__ __forceinline__ float ln_eps2() { return 1.4210854715202004e-14f; }

static __device__ __forceinline__ ushort f2bf(float f) {
    union { float f; unsigned u; } c; c.f = f;
    unsigned r = c.u + 0x7FFFu + ((c.u >> 16) & 1u);   // RNE
    return (ushort)(r >> 16);
}
static __device__ __forceinline__ float bf2f(ushort h) {
    union { unsigned u; float f; } c; c.u = ((unsigned)h) << 16;
    return c.f;
}
static __device__ __forceinline__ unsigned cvtpk_bf16(float a, float b) {
    unsigned r;
    asm volatile("v_cvt_pk_bf16_f32 %0, %1, %2" : "=v"(r) : "v"(a), "v"(b));
    return r;   // lo = bf16(a), hi = bf16(b)
}

// ---------------- Kernel 0a: W1/W2 convert+transpose (proven) ----------------
__global__ __launch_bounds__(256) void wtrans_kernel(
    const float* __restrict__ W1, const float* __restrict__ W2,
    ushort* __restrict__ w1t_hi, ushort* __restrict__ w1t_lo,
    ushort* __restrict__ w2t_hi, ushort* __restrict__ w2t_lo)
{
    __shared__ ushort Th[64][72];
    __shared__ ushort Tl[64][72];
    const int bid = blockIdx.x;              // 0..127
    const float* src; ushort *dh, *dl; int R, C, tile;
    if (bid < 64) {                          // W1
        const int l = bid >> 5; tile = bid & 31;
        src = W1 + (size_t)l * DD * DFF;
        dh = w1t_hi + (size_t)l * DFF * DD; dl = w1t_lo + (size_t)l * DFF * DD;
        R = DD; C = DFF;
    } else {                                 // W2
        const int l = (bid - 64) >> 5; tile = (bid - 64) & 31;
        src = W2 + (size_t)l * DFF * DD;
        dh = w2t_hi + (size_t)l * DD * DFF; dl = w2t_lo + (size_t)l * DD * DFF;
        R = DFF; C = DD;
    }
    const int tilesC = C / 64;
    const int br = (tile / tilesC) * 64, bc = (tile % tilesC) * 64;
    const int tid = threadIdx.x;
#pragma unroll
    for (int i = 0; i < 16; ++i) {
        const int p = i * 256 + tid;
        const int r = p >> 6, c = p & 63;
        const float f = src[(size_t)(br + r) * C + bc + c];
        const ushort h = f2bf(f);
        Th[c][r] = h; Tl[c][r] = f2bf(f - bf2f(h));
    }
    __syncthreads();
#pragma unroll
    for (int i = 0; i < 16; ++i) {
        const int p = i * 256 + tid;
        const int r = p >> 6, c = p & 63;
        dh[(size_t)(bc + r) * R + br + c] = Th[r][c];
        dl[(size_t)(bc + r) * R + br + c] = Tl[r][c];
    }
}

// ---------------- Kernel 0b: Wo -> woT hi/lo [l][256][256] (proven) ----------------
__global__ __launch_bounds__(256) void wotrans_kernel(
    const float* __restrict__ Wo,
    ushort* __restrict__ wh, ushort* __restrict__ wl)
{
    __shared__ float T[64][65];
    const int l = blockIdx.x >> 4, tile = blockIdx.x & 15;
    const int tr = (tile >> 2) * 64;
    const int tc = (tile & 3) * 64;
    const float* src = Wo + (size_t)l * DD * DD;
    ushort* dh = wh + (size_t)l * DD * DD;
    ushort* dl = wl + (size_t)l * DD * DD;
    const int tid = threadIdx.x;
#pragma unroll
    for (int i = 0; i < 16; ++i) {
        const int p = i * 256 + tid;
        const int r = p >> 6, c = p & 63;
        T[r][c] = src[(size_t)(tr + r) * DD + tc + c];
    }
    __syncthreads();
#pragma unroll
    for (int i = 0; i < 16; ++i) {
        const int p = i * 256 + tid;
        const int r = p >> 6, c = p & 63;
        const float f = T[c][r];
        const size_t off = (size_t)(tc + r) * DD + tr + c;
        const ushort h = f2bf(f);
        dh[off] = h;
        dl[off] = f2bf(f - bf2f(h));
    }
}

// ---------------- Kernel 0c: Wq/Wk/Wv -> wqkvT hi/lo [l][768][256] (proven) ----------------
__global__ __launch_bounds__(256) void wqkv_trans_kernel(
    const float* __restrict__ Wq, const float* __restrict__ Wk,
    const float* __restrict__ Wv,
    ushort* __restrict__ qkvT_hi, ushort* __restrict__ qkvT_lo)
{
    __shared__ float T[DKK][DD + 1];
    const int bid = blockIdx.x;              // l*24 + src*8 + h
    const int l = bid / 24, rem = bid % 24, src = rem >> 3, h = rem & 7;
    const float* W = (src == 0 ? Wq : src == 1 ? Wk : Wv)
                     + ((size_t)l * HH + h) * DD * DKK;
    ushort* dh = qkvT_hi + ((size_t)l * 768 + src * 256 + h * 32) * DD;
    ushort* dl = qkvT_lo + ((size_t)l * 768 + src * 256 + h * 32) * DD;
    const int tid = threadIdx.x;
#pragma unroll
    for (int i = 0; i < 32; ++i) {           // W[d][dk] -> T[dk][d]
        const int p = i * 256 + tid;
        T[p & 31][p >> 5] = W[p];
    }
    __syncthreads();
#pragma unroll
    for (int i = 0; i < 32; ++i) {
        const int p = i * 256 + tid;
        const int dk = p >> 8, d = p & 255;
        const float f = T[dk][d];
        const ushort hh = f2bf(f);
        dh[dk * DD + d] = hh;
        dl[dk * DD + d] = f2bf(f - bf2f(hh));
    }
}

// ---------------- Kernel 1: QKV via MFMA, 2-way column split (V written transposed) ----------------
// grid = (B*S/16)*2; 16 rows x 384-col half per WG; 4 waves x 6 tiles.
__global__ __launch_bounds__(256) void qkv_mfma_kernel(
    const float* __restrict__ xin,
    const ushort* __restrict__ wth, const ushort* __restrict__ wtl,
    float* __restrict__ q, ushort* __restrict__ khi, ushort* __restrict__ klo,
    ushort* __restrict__ vt)
{
    __shared__ __align__(16) ushort Xh[16 * XSTR];
    __shared__ __align__(16) ushort Xl[16 * XSTR];

    const int tid = threadIdx.x, wave = tid >> 6, lane = tid & 63;
    const int c16 = lane & 15, g = lane >> 4;
    const int row0 = (blockIdx.x >> 1) * 16;
    const int half = blockIdx.x & 1;

#pragma unroll
    for (int i = 0; i < 16; ++i) {
        const int p = i * 256 + tid;
        const int r = p >> 8, c = p & 255;
        const float f = xin[(size_t)(row0 + r) * DD + c];
        const ushort h = f2bf(f);
        Xh[r * XSTR + c] = h;
        Xl[r * XSTR + c] = f2bf(f - bf2f(h));
    }
    __syncthreads();

    short8 xf_h[8], xf_l[8];
#pragma unroll
    for (int kk = 0; kk < 8; ++kk) {
        xf_h[kk] = *(const short8*)&Xh[c16 * XSTR + kk * 32 + g * 8];
        xf_l[kk] = *(const short8*)&Xl[c16 * XSTR + kk * 32 + g * 8];
    }

    const int b = row0 / SS, s0 = row0 % SS;
    const int wbase = half * 384 + wave * 96;
#pragma unroll 2
    for (int t = 0; t < 6; ++t) {
        const int ncol = wbase + t * 16 + c16;
        const ushort* wh = wth + (size_t)ncol * DD;
        const ushort* wl = wtl + (size_t)ncol * DD;
        f32x4 acc = (f32x4)(0.f);
#pragma unroll
        for (int kk = 0; kk < 8; ++kk) {
            const short8 bh = *(const short8*)(wh + kk * 32 + g * 8);
            const short8 bl = *(const short8*)(wl + kk * 32 + g * 8);
            acc = __builtin_amdgcn_mfma_f32_16x16x32_bf16(xf_h[kk], bh, acc, 0, 0, 0);
            acc = __builtin_amdgcn_mfma_f32_16x16x32_bf16(xf_l[kk], bh, acc, 0, 0, 0);
            acc = __builtin_amdgcn_mfma_f32_16x16x32_bf16(xf_h[kk], bl, acc, 0, 0, 0);
        }
        const int src = ncol >> 8, h = (ncol >> 5) & 7, dk = ncol & 31;
        const size_t base = ((size_t)(b * HH + h) * SS + s0) * DKK + dk;
#pragma unroll
        for (int r = 0; r < 4; ++r) {
            if (src == 0) {
                q[base + (size_t)(4 * g + r) * DKK] = acc[r];
            } else if (src == 1) {
                const size_t off = base + (size_t)(4 * g + r) * DKK;
                const ushort hh = f2bf(acc[r]);
                khi[off] = hh;
                klo[off] = f2bf(acc[r] - bf2f(hh));
            } else {
                // V direct transpose: vt[bh][dv][s]
                vt[((size_t)(b * HH + h) * DVV + dk) * SS + s0 + 4 * g + r] = f2bf(acc[r]);
            }
        }
    }
}

// ---------------- Kernel 2: swapped-operand 32x32 flash attention, split-K=4 (proven best) ----------------
// grid = B*H*(S/128)*NSPLIT; 4 waves x 32 queries each; 64-key tiles.
__global__ __launch_bounds__(256) void attn_mfma_kernel(
    const float* __restrict__ q, const ushort* __restrict__ khi,
    const ushort* __restrict__ klo, const ushort* __restrict__ vt,
    float* __restrict__ opart, float* __restrict__ ml)
{
    __shared__ ushort KhS[64 * KSTR];        // 5120 B
    __shared__ ushort KlS[64 * KSTR];        // 5120 B
    __shared__ ushort VtS[32 * VSTR];        // 4608 B

    const int tid  = threadIdx.x;
    const int wave = tid >> 6;
    const int lane = tid & 63;
    const int c32  = lane & 31;
    const int hi   = lane >> 5;

    const int nqb = SS / 128;                // 16
    const int bh  = blockIdx.x / (nqb * NSPLIT);
    const int rem = blockIdx.x % (nqb * NSPLIT);
    const int qb  = rem / NSPLIT;
    const int sp  = rem % NSPLIT;
    const int qrow = qb * 128 + wave * 32 + c32;

    const float*  qp  = q   + (size_t)bh * SS * DKK;
    const ushort* khp = khi + (size_t)bh * SS * DKK;
    const ushort* klp = klo + (size_t)bh * SS * DKK;
    const ushort* vtp = vt  + (size_t)bh * DVV * SS;

    // Q as B-operand: chunk c holds Q[qrow][c*16 + hi*8 + j], hi/lo split
    short8 qh0, ql0, qh1, ql1;
    {
        const float* qr = qp + (size_t)qrow * DKK + hi * 8;
#pragma unroll
        for (int j = 0; j < 8; ++j) {
            const ushort h = f2bf(qr[j]);
            qh0[j] = (short)h; ql0[j] = (short)f2bf(qr[j] - bf2f(h));
        }
#pragma unroll
        for (int j = 0; j < 8; ++j) {
            const float f = qr[16 + j];
            const ushort h = f2bf(f);
            qh1[j] = (short)h; ql1[j] = (short)f2bf(f - bf2f(h));
        }
    }

    float m = -1e30f, l = 0.f;
    f32x16 oacc = (f32x16)(0.f);
    const f32x16 zero16 = (f32x16)(0.f);

    for (int kt = sp * SCHUNK; kt < (sp + 1) * SCHUNK; kt += 64) {
        // ---- stage K tile hi/lo (64 x 32) and V^T (32 x 64): pure 8B copies ----
#pragma unroll
        for (int i = 0; i < 2; ++i) {
            const int p = i * 256 + tid;       // 0..511
            const int row = p >> 3;            // 0..63
            const int col4 = (p & 7) * 4;      // 0..28
            const uint2 h8 = *(const uint2*)(khp + (size_t)(kt + row) * DKK + col4);
            const uint2 l8 = *(const uint2*)(klp + (size_t)(kt + row) * DKK + col4);
            *(uint2*)&KhS[row * KSTR + col4] = h8;
            *(uint2*)&KlS[row * KSTR + col4] = l8;
        }
#pragma unroll
        for (int i = 0; i < 2; ++i) {
            const int p = i * 256 + tid;       // 0..511
            const int dv = p >> 4;             // 0..31
            const int s8 = (p & 15) * 4;       // 0..60
            const uint2 v8 = *(const uint2*)(vtp + (size_t)dv * SS + kt + s8);
            *(uint2*)&VtS[dv * VSTR + s8] = v8;
        }
        __syncthreads();

        // ---- QK^T swapped: S^T[key][q], 2 key-subtiles of 32 ----
        f32x16 s0, s1;
        {
            const int rb0 = c32 * KSTR + hi * 8;
            const short8 kh0 = *(const short8*)&KhS[rb0];
            const short8 kl0 = *(const short8*)&KlS[rb0];
            const short8 kh1 = *(const short8*)&KhS[rb0 + 16];
            const short8 kl1 = *(const short8*)&KlS[rb0 + 16];
            f32x16 s = __builtin_amdgcn_mfma_f32_32x32x16_bf16(kh0, ql0, zero16, 0, 0, 0);
            s = __builtin_amdgcn_mfma_f32_32x32x16_bf16(kl0, qh0, s, 0, 0, 0);
            s = __builtin_amdgcn_mfma_f32_32x32x16_bf16(kh0, qh0, s, 0, 0, 0);
            s = __builtin_amdgcn_mfma_f32_32x32x16_bf16(kh1, ql1, s, 0, 0, 0);
            s = __builtin_amdgcn_mfma_f32_32x32x16_bf16(kl1, qh1, s, 0, 0, 0);
            s0 = __builtin_amdgcn_mfma_f32_32x32x16_bf16(kh1, qh1, s, 0, 0, 0);
        }
        {
            const int rb1 = (32 + c32) * KSTR + hi * 8;
            const short8 kh0 = *(const short8*)&KhS[rb1];
            const short8 kl0 = *(const short8*)&KlS[rb1];
            const short8 kh1 = *(const short8*)&KhS[rb1 + 16];
            const short8 kl1 = *(const short8*)&KlS[rb1 + 16];
            f32x16 s = __builtin_amdgcn_mfma_f32_32x32x16_bf16(kh0, ql0, zero16, 0, 0, 0);
            s = __builtin_amdgcn_mfma_f32_32x32x16_bf16(kl0, qh0, s, 0, 0, 0);
            s = __builtin_amdgcn_mfma_f32_32x32x16_bf16(kh0, qh0, s, 0, 0, 0);
            s = __builtin_amdgcn_mfma_f32_32x32x16_bf16(kh1, ql1, s, 0, 0, 0);
            s = __builtin_amdgcn_mfma_f32_32x32x16_bf16(kl1, qh1, s, 0, 0, 0);
            s1 = __builtin_amdgcn_mfma_f32_32x32x16_bf16(kh1, qh1, s, 0, 0, 0);
        }

        // ---- online softmax: one query per thread (col=c32) ----
        float tm = s0[0];
#pragma unroll
        for (int j = 1; j < 16; ++j) tm = fmaxf(tm, s0[j]);
#pragma unroll
        for (int j = 0; j < 16; ++j) tm = fmaxf(tm, s1[j]);
        tm = fmaxf(tm, __shfl_xor(tm, 32));
        const float nm = fmaxf(m, tm);
        const float scale = __expf(m - nm);
        m = nm;
        float psum = 0.f;
#pragma unroll
        for (int j = 0; j < 16; ++j) { const float p = __expf(s0[j] - nm); s0[j] = p; psum += p; }
#pragma unroll
        for (int j = 0; j < 16; ++j) { const float p = __expf(s1[j] - nm); s1[j] = p; psum += p; }
        psum += __shfl_xor(psum, 32);
        l = l * scale + psum;
#pragma unroll
        for (int j = 0; j < 16; ++j) oacc[j] *= scale;

        // ---- pack P to bf16 + half-key exchange; build PV B-operands in regs ----
        unsigned w0 = cvtpk_bf16(s0[0],  s0[1]);
        unsigned w1 = cvtpk_bf16(s0[2],  s0[3]);
        unsigned w2 = cvtpk_bf16(s0[4],  s0[5]);
        unsigned w3 = cvtpk_bf16(s0[6],  s0[7]);
        unsigned w4 = cvtpk_bf16(s0[8],  s0[9]);
        unsigned w5 = cvtpk_bf16(s0[10], s0[11]);
        unsigned w6 = cvtpk_bf16(s0[12], s0[13]);
        unsigned w7 = cvtpk_bf16(s0[14], s0[15]);
        unsigned u0 = cvtpk_bf16(s1[0],  s1[1]);
        unsigned u1 = cvtpk_bf16(s1[2],  s1[3]);
        unsigned u2 = cvtpk_bf16(s1[4],  s1[5]);
        unsigned u3 = cvtpk_bf16(s1[6],  s1[7]);
        unsigned u4 = cvtpk_bf16(s1[8],  s1[9]);
        unsigned u5 = cvtpk_bf16(s1[10], s1[11]);
        unsigned u6 = cvtpk_bf16(s1[12], s1[13]);
        unsigned u7 = cvtpk_bf16(s1[14], s1[15]);

        const unsigned x0 = __shfl_xor(hi ? w0 : w2, 32);
        const unsigned x1 = __shfl_xor(hi ? w1 : w3, 32);
        const unsigned x2 = __shfl_xor(hi ? w4 : w6, 32);
        const unsigned x3 = __shfl_xor(hi ? w5 : w7, 32);
        const unsigned y0 = __shfl_xor(hi ? u0 : u2, 32);
        const unsigned y1 = __shfl_xor(hi ? u1 : u3, 32);
        const unsigned y2 = __shfl_xor(hi ? u4 : u6, 32);
        const unsigned y3 = __shfl_xor(hi ? u5 : u7, 32);

        union { unsigned u[4]; short8 s8; } pa, pb, pc, pd;
        if (hi == 0) {
            pa.u[0] = w0; pa.u[1] = w1; pa.u[2] = x0; pa.u[3] = x1;   // keys 0..7
            pb.u[0] = w4; pb.u[1] = w5; pb.u[2] = x2; pb.u[3] = x3;   // keys 16..23
            pc.u[0] = u0; pc.u[1] = u1; pc.u[2] = y0; pc.u[3] = y1;   // keys 32..39
            pd.u[0] = u4; pd.u[1] = u5; pd.u[2] = y2; pd.u[3] = y3;   // keys 48..55
        } else {
            pa.u[0] = x0; pa.u[1] = x1; pa.u[2] = w2; pa.u[3] = w3;   // keys 8..15
            pb.u[0] = x2; pb.u[1] = x3; pb.u[2] = w6; pb.u[3] = w7;   // keys 24..31
            pc.u[0] = y0; pc.u[1] = y1; pc.u[2] = u2; pc.u[3] = u3;   // keys 40..47
            pd.u[0] = y2; pd.u[1] = y3; pd.u[2] = u6; pd.u[3] = u7;   // keys 56..63
        }

        // ---- PV: O^T[dv][q] += V^T-chunks x P-chunks (4 x k=16) ----
        {
            const int vb = c32 * VSTR + hi * 8;
            const short8 v0 = *(const short8*)&VtS[vb];
            const short8 v1 = *(const short8*)&VtS[vb + 16];
            const short8 v2 = *(const short8*)&VtS[vb + 32];
            const short8 v3 = *(const short8*)&VtS[vb + 48];
            oacc = __builtin_amdgcn_mfma_f32_32x32x16_bf16(v0, pa.s8, oacc, 0, 0, 0);
            oacc = __builtin_amdgcn_mfma_f32_32x32x16_bf16(v1, pb.s8, oacc, 0, 0, 0);
            oacc = __builtin_amdgcn_mfma_f32_32x32x16_bf16(v2, pc.s8, oacc, 0, 0, 0);
            oacc = __builtin_amdgcn_mfma_f32_32x32x16_bf16(v3, pd.s8, oacc, 0, 0, 0);
        }
        __syncthreads();
    }

    // ---- epilogue: unnormalized partials + (m,l); dv rows = 8*q4 + 4*hi + r ----
    const size_t pbase = (size_t)(sp * BB * HH + bh) * SS;
    float* op = opart + (pbase + qrow) * DVV;
#pragma unroll
    for (int q4 = 0; q4 < 4; ++q4) {
        f32x4 v;
        v[0] = oacc[4 * q4 + 0]; v[1] = oacc[4 * q4 + 1];
        v[2] = oacc[4 * q4 + 2]; v[3] = oacc[4 * q4 + 3];
        *(f32x4*)(op + 8 * q4 + 4 * hi) = v;
    }
    if (hi == 0) {
        ml[(pbase + qrow) * 2]     = m;
        ml[(pbase + qrow) * 2 + 1] = l;
    }
}

// ---------------- Kernel 2b: split-K merge -> o in concat layout (proven) ----------------
__global__ __launch_bounds__(256) void attn_merge_kernel(
    const float* __restrict__ opart, const float* __restrict__ ml,
    float* __restrict__ o)
{
    const int nch = SS / 128;                // 16
    const int bh = blockIdx.x / nch;
    const int chunk = blockIdx.x % nch;
    const int q0 = chunk * 128;
    const int b = bh >> 3, h = bh & 7;
    const int tid = threadIdx.x;

#pragma unroll
    for (int i = 0; i < 16; ++i) {
        const int p = i * 256 + tid;
        const int ql = p >> 5, dv = p & 31;
        const int qr = q0 + ql;
        float ms[NSPLIT], ls[NSPLIT];
#pragma unroll
        for (int s = 0; s < NSPLIT; ++s) {
            const size_t pb = (size_t)(s * BB * HH + bh) * SS + qr;
            ms[s] = ml[pb * 2];
            ls[s] = ml[pb * 2 + 1];
        }
        float M = ms[0];
#pragma unroll
        for (int s = 1; s < NSPLIT; ++s) M = fmaxf(M, ms[s]);
        float L = 0.f, acc = 0.f;
#pragma unroll
        for (int s = 0; s < NSPLIT; ++s) {
            const float w = __expf(ms[s] - M);
            L += w * ls[s];
            acc += w * opart[((size_t)(s * BB * HH + bh) * SS + qr) * DVV + dv];
        }
        o[(size_t)(b * SS + qr) * (HH * DVV) + h * DVV + dv] = acc / L;
    }
}

// ---------------- Kernel 3: proj via MFMA (proven) ----------------
__global__ __launch_bounds__(256) void proj_mfma_kernel(
    const float* __restrict__ conc, const float* __restrict__ xres,
    const ushort* __restrict__ wth, const ushort* __restrict__ wtl,
    const float* __restrict__ gamma, const float* __restrict__ beta,
    float* __restrict__ xout)
{
    __shared__ __align__(16) ushort Xh[16 * XSTR];
    __shared__ __align__(16) ushort Xl[16 * XSTR];
    __shared__ float Y[16 * YSTR];

    const int tid = threadIdx.x, wave = tid >> 6, lane = tid & 63;
    const int c16 = lane & 15, g = lane >> 4;
    const int row0 = blockIdx.x * 16;

#pragma unroll
    for (int i = 0; i < 16; ++i) {
        const int p = i * 256 + tid;
        const int r = p >> 8, c = p & 255;
        const float f = conc[(size_t)(row0 + r) * DD + c];
        const ushort h = f2bf(f);
        Xh[r * XSTR + c] = h;
        Xl[r * XSTR + c] = f2bf(f - bf2f(h));
    }
    __syncthreads();

    short8 xf_h[8], xf_l[8];
#pragma unroll
    for (int kk = 0; kk < 8; ++kk) {
        xf_h[kk] = *(const short8*)&Xh[c16 * XSTR + kk * 32 + g * 8];
        xf_l[kk] = *(const short8*)&Xl[c16 * XSTR + kk * 32 + g * 8];
    }

    const int wbase = wave * 64;
#pragma unroll 2
    for (int t = 0; t < 4; ++t) {
        const int ncol = wbase + t * 16 + c16;
        const ushort* wh = wth + (size_t)ncol * DD;
        const ushort* wl = wtl + (size_t)ncol * DD;
        f32x4 acc = (f32x4)(0.f);
#pragma unroll
        for (int kk = 0; kk < 8; ++kk) {
            const short8 bh = *(const short8*)(wh + kk * 32 + g * 8);
            const short8 bl = *(const short8*)(wl + kk * 32 + g * 8);
            acc = __builtin_amdgcn_mfma_f32_16x16x32_bf16(xf_h[kk], bh, acc, 0, 0, 0);
            acc = __builtin_amdgcn_mfma_f32_16x16x32_bf16(xf_l[kk], bh, acc, 0, 0, 0);
            acc = __builtin_amdgcn_mfma_f32_16x16x32_bf16(xf_h[kk], bl, acc, 0, 0, 0);
        }
#pragma unroll
        for (int r = 0; r < 4; ++r)
            Y[(4 * g + r) * YSTR + ncol] = acc[r];
    }
    __syncthreads();

    const float g0 = gamma[0], b0 = beta[0];
#pragma unroll
    for (int rr = 0; rr < 4; ++rr) {
        const int row = wave * 4 + rr;
        float v[4];
        float sum = 0.f;
#pragma unroll
        for (int j = 0; j < 4; ++j) {
            const int c = lane + 64 * j;
            v[j] = Y[row * YSTR + c] + xres[(size_t)(row0 + row) * DD + c];
            sum += v[j];
        }
#pragma unroll
        for (int m = 32; m >= 1; m >>= 1) sum += __shfl_xor(sum, m);
        const float mean = sum * (1.0f / DD);
        float var = 0.f;
#pragma unroll
        for (int j = 0; j < 4; ++j) { v[j] -= mean; var += v[j] * v[j]; }
#pragma unroll
        for (int m = 32; m >= 1; m >>= 1) var += __shfl_xor(var, m);
        var *= (1.0f / DD);
        const float rstd = 1.0f / sqrtf(var + ln_eps2());
#pragma unroll
        for (int j = 0; j < 4; ++j)
            xout[(size_t)(row0 + row) * DD + lane + 64 * j] = v[j] * rstd * g0 + b0;
    }
}

// ---------------- Kernel 4: FFN via MFMA + residual + LN (proven) ----------------
__global__ __launch_bounds__(256) void ffn_mfma_kernel(
    const float* __restrict__ xin,
    const ushort* __restrict__ w1th, const ushort* __restrict__ w1tl,
    const ushort* __restrict__ w2th, const ushort* __restrict__ w2tl,
    const float* __restrict__ b1, const float* __restrict__ b2,
    const float* __restrict__ gamma, const float* __restrict__ beta,
    float* __restrict__ xout)
{
    __shared__ __align__(16) char smem[(2 * 16 * XSTR + 2 * 16 * HSTR) * 2];
    ushort* Xh = (ushort*)smem;
    ushort* Xl = Xh + 16 * XSTR;
    ushort* Hh = Xl + 16 * XSTR;
    ushort* Hl = Hh + 16 * HSTR;
    float*  Y  = (float*)smem;

    const int tid  = threadIdx.x;
    const int wave = tid >> 6;
    const int lane = tid & 63;
    const int c16  = lane & 15;
    const int g    = lane >> 4;
    const int row0 = blockIdx.x * 16;

#pragma unroll
    for (int i = 0; i < 16; ++i) {
        const int p = i * 256 + tid;
        const int r = p >> 8, c = p & 255;
        const float f = xin[(size_t)(row0 + r) * DD + c];
        const ushort h = f2bf(f);
        Xh[r * XSTR + c] = h;
        Xl[r * XSTR + c] = f2bf(f - bf2f(h));
    }
    __syncthreads();

    short8 xf_h[8], xf_l[8];
#pragma unroll
    for (int kk = 0; kk < 8; ++kk) {
        xf_h[kk] = *(const short8*)&Xh[c16 * XSTR + kk * 32 + g * 8];
        xf_l[kk] = *(const short8*)&Xl[c16 * XSTR + kk * 32 + g * 8];
    }

    const int wbase = wave * 128;
#pragma unroll 2
    for (int t = 0; t < 8; ++t) {
        const int ncol = wbase + t * 16 + c16;
        const ushort* wh = w1th + (size_t)ncol * DD;
        const ushort* wl = w1tl + (size_t)ncol * DD;
        f32x4 acc = (f32x4)(0.f);
#pragma unroll
        for (int kk = 0; kk < 8; ++kk) {
            const short8 bh = *(const short8*)(wh + kk * 32 + g * 8);
            const short8 bl = *(const short8*)(wl + kk * 32 + g * 8);
            acc = __builtin_amdgcn_mfma_f32_16x16x32_bf16(xf_h[kk], bh, acc, 0, 0, 0);
            acc = __builtin_amdgcn_mfma_f32_16x16x32_bf16(xf_l[kk], bh, acc, 0, 0, 0);
            acc = __builtin_amdgcn_mfma_f32_16x16x32_bf16(xf_h[kk], bl, acc, 0, 0, 0);
        }
        const float bias = b1[ncol];
#pragma unroll
        for (int r = 0; r < 4; ++r) {
            const int mm = 4 * g + r;
            const float hv = fmaxf(acc[r] + bias, 0.f);
            const ushort hh = f2bf(hv);
            Hh[mm * HSTR + ncol] = hh;
            Hl[mm * HSTR + ncol] = f2bf(hv - bf2f(hh));
        }
    }
    __syncthreads();

    const int obase = wave * 64;
    f32x4 acc2[4];
#pragma unroll
    for (int t = 0; t < 4; ++t) acc2[t] = (f32x4)(0.f);
#pragma unroll 2
    for (int kk = 0; kk < 16; ++kk) {
        const short8 ah = *(const short8*)&Hh[c16 * HSTR + kk * 32 + g * 8];
        const short8 al = *(const short8*)&Hl[c16 * HSTR + kk * 32 + g * 8];
#pragma unroll
        for (int t = 0; t < 4; ++t) {
            const int ncol = obase + t * 16 + c16;
            const short8 bh = *(const short8*)(w2th + (size_t)ncol * DFF + kk * 32 + g * 8);
            const short8 bl = *(const short8*)(w2tl + (size_t)ncol * DFF + kk * 32 + g * 8);
            acc2[t] = __builtin_amdgcn_mfma_f32_16x16x32_bf16(ah, bh, acc2[t], 0, 0, 0);
            acc2[t] = __builtin_amdgcn_mfma_f32_16x16x32_bf16(al, bh, acc2[t], 0, 0, 0);
            acc2[t] = __builtin_amdgcn_mfma_f32_16x16x32_bf16(ah, bl, acc2[t], 0, 0, 0);
        }
    }

#pragma unroll
    for (int t = 0; t < 4; ++t) {
        const int ncol = obase + t * 16 + c16;
#pragma unroll
        for (int r = 0; r < 4; ++r)
            Y[(4 * g + r) * YSTR + ncol] = acc2[t][r];
    }
    __syncthreads();

    const float g0 = gamma[0], b0 = beta[0];
#pragma unroll
    for (int rr = 0; rr < 4; ++rr) {
        const int row = wave * 4 + rr;
        float v[4];
        float sum = 0.f;
#pragma unroll
        for (int j = 0; j < 4; ++j) {
            const int c = lane + 64 * j;
            v[j] = Y[row * YSTR + c] + b2[c] + xin[(size_t)(row0 + row) * DD + c];
            sum += v[j];
        }
#pragma unroll
        for (int m = 32; m >= 1; m >>= 1) sum += __shfl_xor(sum, m);
        const float mean = sum * (1.0f / DD);
        float var = 0.f;
#pragma unroll
        for (int j = 0; j < 4; ++j) { v[j] -= mean; var += v[j] * v[j]; }
#pragma unroll
        for (int m = 32; m >= 1; m >>= 1) var += __shfl_xor(var, m);
        var *= (1.0f / DD);
        const float rstd = 1.0f / sqrtf(var + ln_eps2());
#pragma unroll
        for (int j = 0; j < 4; ++j)
            xout[(size_t)(row0 + row) * DD + lane + 64 * j] = v[j] * rstd * g0 + b0;
    }
}

// ---------------- host launch ----------------
extern "C" void kernel_launch(void* const* d_in, const int* in_sizes, int n_in,
                              void* d_out, int out_size, void* d_ws, size_t ws_size,
                              hipStream_t stream) {
    const float* x     = (const float*)d_in[0];
    const float* Wq    = (const float*)d_in[1];
    const float* Wk    = (const float*)d_in[2];
    const float* Wv    = (const float*)d_in[3];
    const float* Wo    = (const float*)d_in[4];
    const float* W1    = (const float*)d_in[5];
    const float* b1    = (const float*)d_in[6];
    const float* W2    = (const float*)d_in[7];
    const float* b2    = (const float*)d_in[8];
    const float* gamma = (const float*)d_in[9];
    const float* beta  = (const float*)d_in[10];
    float* out = (float*)d_out;

    const size_t NTOK = (size_t)BB * SS * DD;       // 1,048,576
    const size_t WFF  = (size_t)NL * DFF * DD;      // 262,144
    const size_t WOO  = (size_t)NL * DD * DD;       // 131,072
    const size_t WQKV = (size_t)NL * 768 * DD;      // 393,216
    float*  q    = (float*)d_ws;
    ushort* khi  = (ushort*)(q + NTOK);
    ushort* klo  = khi + NTOK;
    ushort* vt   = klo + NTOK;
    float*  o    = (float*)(vt + NTOK);
    float*  xa   = o + NTOK;
    float*  xb   = xa + NTOK;
    ushort* w1th = (ushort*)(xb + NTOK);
    ushort* w1tl = w1th + WFF;
    ushort* w2th = w1tl + WFF;
    ushort* w2tl = w2th + WFF;
    ushort* woth = w2tl + WFF;
    ushort* wotl = woth + WOO;
    ushort* wqth = wotl + WOO;
    ushort* wqtl = wqth + WQKV;
    float*  opart = (float*)(wqtl + WQKV);          // NSPLIT*B*H*S*DVV f32 = 16 MB
    float*  ml    = opart + (size_t)NSPLIT * BB * HH * SS * DVV;  // 1 MB

    wtrans_kernel<<<128, 256, 0, stream>>>(W1, W2, w1th, w1tl, w2th, w2tl);
    wotrans_kernel<<<NL * 16, 256, 0, stream>>>(Wo, woth, wotl);
    wqkv_trans_kernel<<<48, 256, 0, stream>>>(Wq, Wk, Wv, wqth, wqtl);

    const float* cur = x;
    for (int l = 0; l < NL; ++l) {
        qkv_mfma_kernel<<<2 * BB * SS / 16, 256, 0, stream>>>(
            cur, wqth + (size_t)l * 768 * DD, wqtl + (size_t)l * 768 * DD,
            q, khi, klo, vt);
        attn_mfma_kernel<<<BB * HH * (SS / 128) * NSPLIT, 256, 0, stream>>>(
            q, khi, klo, vt, opart, ml);
        attn_merge_kernel<<<BB * HH * (SS / 128), 256, 0, stream>>>(opart, ml, o);
        proj_mfma_kernel<<<BB * SS / 16, 256, 0, stream>>>(
            o, cur, woth + (size_t)l * DD * DD, wotl + (size_t)l * DD * DD,
            gamma + 2 * l, beta + 2 * l, xa);
        float* nxt = (l == NL - 1) ? out : xb;
        ffn_mfma_kernel<<<BB * SS / 16, 256, 0, stream>>>(
            xa, w1th + (size_t)l * DFF * DD, w1tl + (size_t)l * DFF * DD,
            w2th + (size_t)l * DD * DFF, w2tl + (size_t)l * DD * DFF,
            b1 + (size_t)l * DFF, b2 + (size_t)l * DD,
            gamma + 2 * l + 1, beta + 2 * l + 1, nxt);
        cur = nxt;
    }
}

// Round 24
// 244.616 us; speedup vs baseline: 1.0694x; 1.0011x over previous
//
#include <hip/hip_runtime.h>
#include <math.h>

#define BB 2
#define SS 2048
#define DD 256
#define HH 8
#define DKK 32
#define DVV 32
#define DFF 512
#define NL 2

// attention tiling
#define KSTR 40
#define VSTR 72
#define NSPLIT 4
#define SCHUNK (SS / NSPLIT)   // 512 keys per block

// gemm tiling
#define XSTR 264     // 16-row X tile stride (ushort)
#define HSTR 520     // 16-row H tile stride (ushort)
#define YSTR 260     // Y tile stride (float)

typedef __attribute__((ext_vector_type(8))) short short8;
typedef __attribute__((ext_vector_type(4))) float f32x4;
typedef __attribute__((ext_vector_type(16))) float f32x16;

static __device__ __forceinline__ float ln_eps2() { return 1.4210854715202004e-14f; }

static __device__ __forceinline__ ushort f2bf(float f) {
    union { float f; unsigned u; } c; c.f = f;
    unsigned r = c.u + 0x7FFFu + ((c.u >> 16) & 1u);   // RNE
    return (ushort)(r >> 16);
}
static __device__ __forceinline__ float bf2f(ushort h) {
    union { unsigned u; float f; } c; c.u = ((unsigned)h) << 16;
    return c.f;
}
static __device__ __forceinline__ unsigned cvtpk_bf16(float a, float b) {
    unsigned r;
    asm volatile("v_cvt_pk_bf16_f32 %0, %1, %2" : "=v"(r) : "v"(a), "v"(b));
    return r;   // lo = bf16(a), hi = bf16(b)
}

// ---------------- Kernel 0a: W1/W2 convert+transpose (proven) ----------------
__global__ __launch_bounds__(256) void wtrans_kernel(
    const float* __restrict__ W1, const float* __restrict__ W2,
    ushort* __restrict__ w1t_hi, ushort* __restrict__ w1t_lo,
    ushort* __restrict__ w2t_hi, ushort* __restrict__ w2t_lo)
{
    __shared__ ushort Th[64][72];
    __shared__ ushort Tl[64][72];
    const int bid = blockIdx.x;              // 0..127
    const float* src; ushort *dh, *dl; int R, C, tile;
    if (bid < 64) {                          // W1
        const int l = bid >> 5; tile = bid & 31;
        src = W1 + (size_t)l * DD * DFF;
        dh = w1t_hi + (size_t)l * DFF * DD; dl = w1t_lo + (size_t)l * DFF * DD;
        R = DD; C = DFF;
    } else {                                 // W2
        const int l = (bid - 64) >> 5; tile = (bid - 64) & 31;
        src = W2 + (size_t)l * DFF * DD;
        dh = w2t_hi + (size_t)l * DD * DFF; dl = w2t_lo + (size_t)l * DD * DFF;
        R = DFF; C = DD;
    }
    const int tilesC = C / 64;
    const int br = (tile / tilesC) * 64, bc = (tile % tilesC) * 64;
    const int tid = threadIdx.x;
#pragma unroll
    for (int i = 0; i < 16; ++i) {
        const int p = i * 256 + tid;
        const int r = p >> 6, c = p & 63;
        const float f = src[(size_t)(br + r) * C + bc + c];
        const ushort h = f2bf(f);
        Th[c][r] = h; Tl[c][r] = f2bf(f - bf2f(h));
    }
    __syncthreads();
#pragma unroll
    for (int i = 0; i < 16; ++i) {
        const int p = i * 256 + tid;
        const int r = p >> 6, c = p & 63;
        dh[(size_t)(bc + r) * R + br + c] = Th[r][c];
        dl[(size_t)(bc + r) * R + br + c] = Tl[r][c];
    }
}

// ---------------- Kernel 0b: Wo -> woT hi/lo [l][256][256] (proven) ----------------
__global__ __launch_bounds__(256) void wotrans_kernel(
    const float* __restrict__ Wo,
    ushort* __restrict__ wh, ushort* __restrict__ wl)
{
    __shared__ float T[64][65];
    const int l = blockIdx.x >> 4, tile = blockIdx.x & 15;
    const int tr = (tile >> 2) * 64;
    const int tc = (tile & 3) * 64;
    const float* src = Wo + (size_t)l * DD * DD;
    ushort* dh = wh + (size_t)l * DD * DD;
    ushort* dl = wl + (size_t)l * DD * DD;
    const int tid = threadIdx.x;
#pragma unroll
    for (int i = 0; i < 16; ++i) {
        const int p = i * 256 + tid;
        const int r = p >> 6, c = p & 63;
        T[r][c] = src[(size_t)(tr + r) * DD + tc + c];
    }
    __syncthreads();
#pragma unroll
    for (int i = 0; i < 16; ++i) {
        const int p = i * 256 + tid;
        const int r = p >> 6, c = p & 63;
        const float f = T[c][r];
        const size_t off = (size_t)(tc + r) * DD + tr + c;
        const ushort h = f2bf(f);
        dh[off] = h;
        dl[off] = f2bf(f - bf2f(h));
    }
}

// ---------------- Kernel 0c: Wq/Wk/Wv -> wqkvT hi/lo [l][768][256] (proven) ----------------
__global__ __launch_bounds__(256) void wqkv_trans_kernel(
    const float* __restrict__ Wq, const float* __restrict__ Wk,
    const float* __restrict__ Wv,
    ushort* __restrict__ qkvT_hi, ushort* __restrict__ qkvT_lo)
{
    __shared__ float T[DKK][DD + 1];
    const int bid = blockIdx.x;              // l*24 + src*8 + h
    const int l = bid / 24, rem = bid % 24, src = rem >> 3, h = rem & 7;
    const float* W = (src == 0 ? Wq : src == 1 ? Wk : Wv)
                     + ((size_t)l * HH + h) * DD * DKK;
    ushort* dh = qkvT_hi + ((size_t)l * 768 + src * 256 + h * 32) * DD;
    ushort* dl = qkvT_lo + ((size_t)l * 768 + src * 256 + h * 32) * DD;
    const int tid = threadIdx.x;
#pragma unroll
    for (int i = 0; i < 32; ++i) {           // W[d][dk] -> T[dk][d]
        const int p = i * 256 + tid;
        T[p & 31][p >> 5] = W[p];
    }
    __syncthreads();
#pragma unroll
    for (int i = 0; i < 32; ++i) {
        const int p = i * 256 + tid;
        const int dk = p >> 8, d = p & 255;
        const float f = T[dk][d];
        const ushort hh = f2bf(f);
        dh[dk * DD + d] = hh;
        dl[dk * DD + d] = f2bf(f - bf2f(hh));
    }
}

// ---------------- Kernel 1: QKV via MFMA, 2-way column split (V written transposed) ----------------
// grid = (B*S/16)*2; 16 rows x 384-col half per WG; 4 waves x 6 tiles.
__global__ __launch_bounds__(256) void qkv_mfma_kernel(
    const float* __restrict__ xin,
    const ushort* __restrict__ wth, const ushort* __restrict__ wtl,
    float* __restrict__ q, ushort* __restrict__ khi, ushort* __restrict__ klo,
    ushort* __restrict__ vt)
{
    __shared__ __align__(16) ushort Xh[16 * XSTR];
    __shared__ __align__(16) ushort Xl[16 * XSTR];

    const int tid = threadIdx.x, wave = tid >> 6, lane = tid & 63;
    const int c16 = lane & 15, g = lane >> 4;
    const int row0 = (blockIdx.x >> 1) * 16;
    const int half = blockIdx.x & 1;

#pragma unroll
    for (int i = 0; i < 16; ++i) {
        const int p = i * 256 + tid;
        const int r = p >> 8, c = p & 255;
        const float f = xin[(size_t)(row0 + r) * DD + c];
        const ushort h = f2bf(f);
        Xh[r * XSTR + c] = h;
        Xl[r * XSTR + c] = f2bf(f - bf2f(h));
    }
    __syncthreads();

    short8 xf_h[8], xf_l[8];
#pragma unroll
    for (int kk = 0; kk < 8; ++kk) {
        xf_h[kk] = *(const short8*)&Xh[c16 * XSTR + kk * 32 + g * 8];
        xf_l[kk] = *(const short8*)&Xl[c16 * XSTR + kk * 32 + g * 8];
    }

    const int b = row0 / SS, s0 = row0 % SS;
    const int wbase = half * 384 + wave * 96;
#pragma unroll 2
    for (int t = 0; t < 6; ++t) {
        const int ncol = wbase + t * 16 + c16;
        const ushort* wh = wth + (size_t)ncol * DD;
        const ushort* wl = wtl + (size_t)ncol * DD;
        f32x4 acc = (f32x4)(0.f);
#pragma unroll
        for (int kk = 0; kk < 8; ++kk) {
            const short8 bh = *(const short8*)(wh + kk * 32 + g * 8);
            const short8 bl = *(const short8*)(wl + kk * 32 + g * 8);
            acc = __builtin_amdgcn_mfma_f32_16x16x32_bf16(xf_h[kk], bh, acc, 0, 0, 0);
            acc = __builtin_amdgcn_mfma_f32_16x16x32_bf16(xf_l[kk], bh, acc, 0, 0, 0);
            acc = __builtin_amdgcn_mfma_f32_16x16x32_bf16(xf_h[kk], bl, acc, 0, 0, 0);
        }
        const int src = ncol >> 8, h = (ncol >> 5) & 7, dk = ncol & 31;
        const size_t base = ((size_t)(b * HH + h) * SS + s0) * DKK + dk;
#pragma unroll
        for (int r = 0; r < 4; ++r) {
            if (src == 0) {
                q[base + (size_t)(4 * g + r) * DKK] = acc[r];
            } else if (src == 1) {
                const size_t off = base + (size_t)(4 * g + r) * DKK;
                const ushort hh = f2bf(acc[r]);
                khi[off] = hh;
                klo[off] = f2bf(acc[r] - bf2f(hh));
            } else {
                // V direct transpose: vt[bh][dv][s]
                vt[((size_t)(b * HH + h) * DVV + dk) * SS + s0 + 4 * g + r] = f2bf(acc[r]);
            }
        }
    }
}

// ---------------- Kernel 2: swapped-operand 32x32 flash attention, split-K=4 (proven best) ----------------
// grid = B*H*(S/128)*NSPLIT; 4 waves x 32 queries each; 64-key tiles.
__global__ __launch_bounds__(256) void attn_mfma_kernel(
    const float* __restrict__ q, const ushort* __restrict__ khi,
    const ushort* __restrict__ klo, const ushort* __restrict__ vt,
    float* __restrict__ opart, float* __restrict__ ml)
{
    __shared__ ushort KhS[64 * KSTR];        // 5120 B
    __shared__ ushort KlS[64 * KSTR];        // 5120 B
    __shared__ ushort VtS[32 * VSTR];        // 4608 B

    const int tid  = threadIdx.x;
    const int wave = tid >> 6;
    const int lane = tid & 63;
    const int c32  = lane & 31;
    const int hi   = lane >> 5;

    const int nqb = SS / 128;                // 16
    const int bh  = blockIdx.x / (nqb * NSPLIT);
    const int rem = blockIdx.x % (nqb * NSPLIT);
    const int qb  = rem / NSPLIT;
    const int sp  = rem % NSPLIT;
    const int qrow = qb * 128 + wave * 32 + c32;

    const float*  qp  = q   + (size_t)bh * SS * DKK;
    const ushort* khp = khi + (size_t)bh * SS * DKK;
    const ushort* klp = klo + (size_t)bh * SS * DKK;
    const ushort* vtp = vt  + (size_t)bh * DVV * SS;

    // Q as B-operand: chunk c holds Q[qrow][c*16 + hi*8 + j], hi/lo split
    short8 qh0, ql0, qh1, ql1;
    {
        const float* qr = qp + (size_t)qrow * DKK + hi * 8;
#pragma unroll
        for (int j = 0; j < 8; ++j) {
            const ushort h = f2bf(qr[j]);
            qh0[j] = (short)h; ql0[j] = (short)f2bf(qr[j] - bf2f(h));
        }
#pragma unroll
        for (int j = 0; j < 8; ++j) {
            const float f = qr[16 + j];
            const ushort h = f2bf(f);
            qh1[j] = (short)h; ql1[j] = (short)f2bf(f - bf2f(h));
        }
    }

    float m = -1e30f, l = 0.f;
    f32x16 oacc = (f32x16)(0.f);
    const f32x16 zero16 = (f32x16)(0.f);

    for (int kt = sp * SCHUNK; kt < (sp + 1) * SCHUNK; kt += 64) {
        // ---- stage K tile hi/lo (64 x 32) and V^T (32 x 64): pure 8B copies ----
#pragma unroll
        for (int i = 0; i < 2; ++i) {
            const int p = i * 256 + tid;       // 0..511
            const int row = p >> 3;            // 0..63
            const int col4 = (p & 7) * 4;      // 0..28
            const uint2 h8 = *(const uint2*)(khp + (size_t)(kt + row) * DKK + col4);
            const uint2 l8 = *(const uint2*)(klp + (size_t)(kt + row) * DKK + col4);
            *(uint2*)&KhS[row * KSTR + col4] = h8;
            *(uint2*)&KlS[row * KSTR + col4] = l8;
        }
#pragma unroll
        for (int i = 0; i < 2; ++i) {
            const int p = i * 256 + tid;       // 0..511
            const int dv = p >> 4;             // 0..31
            const int s8 = (p & 15) * 4;       // 0..60
            const uint2 v8 = *(const uint2*)(vtp + (size_t)dv * SS + kt + s8);
            *(uint2*)&VtS[dv * VSTR + s8] = v8;
        }
        __syncthreads();

        // ---- QK^T swapped: S^T[key][q], 2 key-subtiles of 32 ----
        f32x16 s0, s1;
        {
            const int rb0 = c32 * KSTR + hi * 8;
            const short8 kh0 = *(const short8*)&KhS[rb0];
            const short8 kl0 = *(const short8*)&KlS[rb0];
            const short8 kh1 = *(const short8*)&KhS[rb0 + 16];
            const short8 kl1 = *(const short8*)&KlS[rb0 + 16];
            f32x16 s = __builtin_amdgcn_mfma_f32_32x32x16_bf16(kh0, ql0, zero16, 0, 0, 0);
            s = __builtin_amdgcn_mfma_f32_32x32x16_bf16(kl0, qh0, s, 0, 0, 0);
            s = __builtin_amdgcn_mfma_f32_32x32x16_bf16(kh0, qh0, s, 0, 0, 0);
            s = __builtin_amdgcn_mfma_f32_32x32x16_bf16(kh1, ql1, s, 0, 0, 0);
            s = __builtin_amdgcn_mfma_f32_32x32x16_bf16(kl1, qh1, s, 0, 0, 0);
            s0 = __builtin_amdgcn_mfma_f32_32x32x16_bf16(kh1, qh1, s, 0, 0, 0);
        }
        {
            const int rb1 = (32 + c32) * KSTR + hi * 8;
            const short8 kh0 = *(const short8*)&KhS[rb1];
            const short8 kl0 = *(const short8*)&KlS[rb1];
            const short8 kh1 = *(const short8*)&KhS[rb1 + 16];
            const short8 kl1 = *(const short8*)&KlS[rb1 + 16];
            f32x16 s = __builtin_amdgcn_mfma_f32_32x32x16_bf16(kh0, ql0, zero16, 0, 0, 0);
            s = __builtin_amdgcn_mfma_f32_32x32x16_bf16(kl0, qh0, s, 0, 0, 0);
            s = __builtin_amdgcn_mfma_f32_32x32x16_bf16(kh0, qh0, s, 0, 0, 0);
            s = __builtin_amdgcn_mfma_f32_32x32x16_bf16(kh1, ql1, s, 0, 0, 0);
            s = __builtin_amdgcn_mfma_f32_32x32x16_bf16(kl1, qh1, s, 0, 0, 0);
            s1 = __builtin_amdgcn_mfma_f32_32x32x16_bf16(kh1, qh1, s, 0, 0, 0);
        }

        // ---- online softmax: one query per thread (col=c32) ----
        float tm = s0[0];
#pragma unroll
        for (int j = 1; j < 16; ++j) tm = fmaxf(tm, s0[j]);
#pragma unroll
        for (int j = 0; j < 16; ++j) tm = fmaxf(tm, s1[j]);
        tm = fmaxf(tm, __shfl_xor(tm, 32));
        const float nm = fmaxf(m, tm);
        const float scale = __expf(m - nm);
        m = nm;
        float psum = 0.f;
#pragma unroll
        for (int j = 0; j < 16; ++j) { const float p = __expf(s0[j] - nm); s0[j] = p; psum += p; }
#pragma unroll
        for (int j = 0; j < 16; ++j) { const float p = __expf(s1[j] - nm); s1[j] = p; psum += p; }
        psum += __shfl_xor(psum, 32);
        l = l * scale + psum;
#pragma unroll
        for (int j = 0; j < 16; ++j) oacc[j] *= scale;

        // ---- pack P to bf16 + half-key exchange; build PV B-operands in regs ----
        unsigned w0 = cvtpk_bf16(s0[0],  s0[1]);
        unsigned w1 = cvtpk_bf16(s0[2],  s0[3]);
        unsigned w2 = cvtpk_bf16(s0[4],  s0[5]);
        unsigned w3 = cvtpk_bf16(s0[6],  s0[7]);
        unsigned w4 = cvtpk_bf16(s0[8],  s0[9]);
        unsigned w5 = cvtpk_bf16(s0[10], s0[11]);
        unsigned w6 = cvtpk_bf16(s0[12], s0[13]);
        unsigned w7 = cvtpk_bf16(s0[14], s0[15]);
        unsigned u0 = cvtpk_bf16(s1[0],  s1[1]);
        unsigned u1 = cvtpk_bf16(s1[2],  s1[3]);
        unsigned u2 = cvtpk_bf16(s1[4],  s1[5]);
        unsigned u3 = cvtpk_bf16(s1[6],  s1[7]);
        unsigned u4 = cvtpk_bf16(s1[8],  s1[9]);
        unsigned u5 = cvtpk_bf16(s1[10], s1[11]);
        unsigned u6 = cvtpk_bf16(s1[12], s1[13]);
        unsigned u7 = cvtpk_bf16(s1[14], s1[15]);

        const unsigned x0 = __shfl_xor(hi ? w0 : w2, 32);
        const unsigned x1 = __shfl_xor(hi ? w1 : w3, 32);
        const unsigned x2 = __shfl_xor(hi ? w4 : w6, 32);
        const unsigned x3 = __shfl_xor(hi ? w5 : w7, 32);
        const unsigned y0 = __shfl_xor(hi ? u0 : u2, 32);
        const unsigned y1 = __shfl_xor(hi ? u1 : u3, 32);
        const unsigned y2 = __shfl_xor(hi ? u4 : u6, 32);
        const unsigned y3 = __shfl_xor(hi ? u5 : u7, 32);

        union { unsigned u[4]; short8 s8; } pa, pb, pc, pd;
        if (hi == 0) {
            pa.u[0] = w0; pa.u[1] = w1; pa.u[2] = x0; pa.u[3] = x1;   // keys 0..7
            pb.u[0] = w4; pb.u[1] = w5; pb.u[2] = x2; pb.u[3] = x3;   // keys 16..23
            pc.u[0] = u0; pc.u[1] = u1; pc.u[2] = y0; pc.u[3] = y1;   // keys 32..39
            pd.u[0] = u4; pd.u[1] = u5; pd.u[2] = y2; pd.u[3] = y3;   // keys 48..55
        } else {
            pa.u[0] = x0; pa.u[1] = x1; pa.u[2] = w2; pa.u[3] = w3;   // keys 8..15
            pb.u[0] = x2; pb.u[1] = x3; pb.u[2] = w6; pb.u[3] = w7;   // keys 24..31
            pc.u[0] = y0; pc.u[1] = y1; pc.u[2] = u2; pc.u[3] = u3;   // keys 40..47
            pd.u[0] = y2; pd.u[1] = y3; pd.u[2] = u6; pd.u[3] = u7;   // keys 56..63
        }

        // ---- PV: O^T[dv][q] += V^T-chunks x P-chunks (4 x k=16) ----
        {
            const int vb = c32 * VSTR + hi * 8;
            const short8 v0 = *(const short8*)&VtS[vb];
            const short8 v1 = *(const short8*)&VtS[vb + 16];
            const short8 v2 = *(const short8*)&VtS[vb + 32];
            const short8 v3 = *(const short8*)&VtS[vb + 48];
            oacc = __builtin_amdgcn_mfma_f32_32x32x16_bf16(v0, pa.s8, oacc, 0, 0, 0);
            oacc = __builtin_amdgcn_mfma_f32_32x32x16_bf16(v1, pb.s8, oacc, 0, 0, 0);
            oacc = __builtin_amdgcn_mfma_f32_32x32x16_bf16(v2, pc.s8, oacc, 0, 0, 0);
            oacc = __builtin_amdgcn_mfma_f32_32x32x16_bf16(v3, pd.s8, oacc, 0, 0, 0);
        }
        __syncthreads();
    }

    // ---- epilogue: unnormalized partials + (m,l); dv rows = 8*q4 + 4*hi + r ----
    const size_t pbase = (size_t)(sp * BB * HH + bh) * SS;
    float* op = opart + (pbase + qrow) * DVV;
#pragma unroll
    for (int q4 = 0; q4 < 4; ++q4) {
        f32x4 v;
        v[0] = oacc[4 * q4 + 0]; v[1] = oacc[4 * q4 + 1];
        v[2] = oacc[4 * q4 + 2]; v[3] = oacc[4 * q4 + 3];
        *(f32x4*)(op + 8 * q4 + 4 * hi) = v;
    }
    if (hi == 0) {
        ml[(pbase + qrow) * 2]     = m;
        ml[(pbase + qrow) * 2 + 1] = l;
    }
}

// ---------------- Kernel 2b: split-K merge -> o in concat layout (proven) ----------------
__global__ __launch_bounds__(256) void attn_merge_kernel(
    const float* __restrict__ opart, const float* __restrict__ ml,
    float* __restrict__ o)
{
    const int nch = SS / 128;                // 16
    const int bh = blockIdx.x / nch;
    const int chunk = blockIdx.x % nch;
    const int q0 = chunk * 128;
    const int b = bh >> 3, h = bh & 7;
    const int tid = threadIdx.x;

#pragma unroll
    for (int i = 0; i < 16; ++i) {
        const int p = i * 256 + tid;
        const int ql = p >> 5, dv = p & 31;
        const int qr = q0 + ql;
        float ms[NSPLIT], ls[NSPLIT];
#pragma unroll
        for (int s = 0; s < NSPLIT; ++s) {
            const size_t pb = (size_t)(s * BB * HH + bh) * SS + qr;
            ms[s] = ml[pb * 2];
            ls[s] = ml[pb * 2 + 1];
        }
        float M = ms[0];
#pragma unroll
        for (int s = 1; s < NSPLIT; ++s) M = fmaxf(M, ms[s]);
        float L = 0.f, acc = 0.f;
#pragma unroll
        for (int s = 0; s < NSPLIT; ++s) {
            const float w = __expf(ms[s] - M);
            L += w * ls[s];
            acc += w * opart[((size_t)(s * BB * HH + bh) * SS + qr) * DVV + dv];
        }
        o[(size_t)(b * SS + qr) * (HH * DVV) + h * DVV + dv] = acc / L;
    }
}

// ---------------- Kernel 3: proj via MFMA (proven) ----------------
__global__ __launch_bounds__(256) void proj_mfma_kernel(
    const float* __restrict__ conc, const float* __restrict__ xres,
    const ushort* __restrict__ wth, const ushort* __restrict__ wtl,
    const float* __restrict__ gamma, const float* __restrict__ beta,
    float* __restrict__ xout)
{
    __shared__ __align__(16) ushort Xh[16 * XSTR];
    __shared__ __align__(16) ushort Xl[16 * XSTR];
    __shared__ float Y[16 * YSTR];

    const int tid = threadIdx.x, wave = tid >> 6, lane = tid & 63;
    const int c16 = lane & 15, g = lane >> 4;
    const int row0 = blockIdx.x * 16;

#pragma unroll
    for (int i = 0; i < 16; ++i) {
        const int p = i * 256 + tid;
        const int r = p >> 8, c = p & 255;
        const float f = conc[(size_t)(row0 + r) * DD + c];
        const ushort h = f2bf(f);
        Xh[r * XSTR + c] = h;
        Xl[r * XSTR + c] = f2bf(f - bf2f(h));
    }
    __syncthreads();

    short8 xf_h[8], xf_l[8];
#pragma unroll
    for (int kk = 0; kk < 8; ++kk) {
        xf_h[kk] = *(const short8*)&Xh[c16 * XSTR + kk * 32 + g * 8];
        xf_l[kk] = *(const short8*)&Xl[c16 * XSTR + kk * 32 + g * 8];
    }

    const int wbase = wave * 64;
#pragma unroll 2
    for (int t = 0; t < 4; ++t) {
        const int ncol = wbase + t * 16 + c16;
        const ushort* wh = wth + (size_t)ncol * DD;
        const ushort* wl = wtl + (size_t)ncol * DD;
        f32x4 acc = (f32x4)(0.f);
#pragma unroll
        for (int kk = 0; kk < 8; ++kk) {
            const short8 bh = *(const short8*)(wh + kk * 32 + g * 8);
            const short8 bl = *(const short8*)(wl + kk * 32 + g * 8);
            acc = __builtin_amdgcn_mfma_f32_16x16x32_bf16(xf_h[kk], bh, acc, 0, 0, 0);
            acc = __builtin_amdgcn_mfma_f32_16x16x32_bf16(xf_l[kk], bh, acc, 0, 0, 0);
            acc = __builtin_amdgcn_mfma_f32_16x16x32_bf16(xf_h[kk], bl, acc, 0, 0, 0);
        }
#pragma unroll
        for (int r = 0; r < 4; ++r)
            Y[(4 * g + r) * YSTR + ncol] = acc[r];
    }
    __syncthreads();

    const float g0 = gamma[0], b0 = beta[0];
#pragma unroll
    for (int rr = 0; rr < 4; ++rr) {
        const int row = wave * 4 + rr;
        float v[4];
        float sum = 0.f;
#pragma unroll
        for (int j = 0; j < 4; ++j) {
            const int c = lane + 64 * j;
            v[j] = Y[row * YSTR + c] + xres[(size_t)(row0 + row) * DD + c];
            sum += v[j];
        }
#pragma unroll
        for (int m = 32; m >= 1; m >>= 1) sum += __shfl_xor(sum, m);
        const float mean = sum * (1.0f / DD);
        float var = 0.f;
#pragma unroll
        for (int j = 0; j < 4; ++j) { v[j] -= mean; var += v[j] * v[j]; }
#pragma unroll
        for (int m = 32; m >= 1; m >>= 1) var += __shfl_xor(var, m);
        var *= (1.0f / DD);
        const float rstd = 1.0f / sqrtf(var + ln_eps2());
#pragma unroll
        for (int j = 0; j < 4; ++j)
            xout[(size_t)(row0 + row) * DD + lane + 64 * j] = v[j] * rstd * g0 + b0;
    }
}

// ---------------- Kernel 4: FFN via MFMA + residual + LN (proven) ----------------
__global__ __launch_bounds__(256) void ffn_mfma_kernel(
    const float* __restrict__ xin,
    const ushort* __restrict__ w1th, const ushort* __restrict__ w1tl,
    const ushort* __restrict__ w2th, const ushort* __restrict__ w2tl,
    const float* __restrict__ b1, const float* __restrict__ b2,
    const float* __restrict__ gamma, const float* __restrict__ beta,
    float* __restrict__ xout)
{
    __shared__ __align__(16) char smem[(2 * 16 * XSTR + 2 * 16 * HSTR) * 2];
    ushort* Xh = (ushort*)smem;
    ushort* Xl = Xh + 16 * XSTR;
    ushort* Hh = Xl + 16 * XSTR;
    ushort* Hl = Hh + 16 * HSTR;
    float*  Y  = (float*)smem;

    const int tid  = threadIdx.x;
    const int wave = tid >> 6;
    const int lane = tid & 63;
    const int c16  = lane & 15;
    const int g    = lane >> 4;
    const int row0 = blockIdx.x * 16;

#pragma unroll
    for (int i = 0; i < 16; ++i) {
        const int p = i * 256 + tid;
        const int r = p >> 8, c = p & 255;
        const float f = xin[(size_t)(row0 + r) * DD + c];
        const ushort h = f2bf(f);
        Xh[r * XSTR + c] = h;
        Xl[r * XSTR + c] = f2bf(f - bf2f(h));
    }
    __syncthreads();

    short8 xf_h[8], xf_l[8];
#pragma unroll
    for (int kk = 0; kk < 8; ++kk) {
        xf_h[kk] = *(const short8*)&Xh[c16 * XSTR + kk * 32 + g * 8];
        xf_l[kk] = *(const short8*)&Xl[c16 * XSTR + kk * 32 + g * 8];
    }

    const int wbase = wave * 128;
#pragma unroll 2
    for (int t = 0; t < 8; ++t) {
        const int ncol = wbase + t * 16 + c16;
        const ushort* wh = w1th + (size_t)ncol * DD;
        const ushort* wl = w1tl + (size_t)ncol * DD;
        f32x4 acc = (f32x4)(0.f);
#pragma unroll
        for (int kk = 0; kk < 8; ++kk) {
            const short8 bh = *(const short8*)(wh + kk * 32 + g * 8);
            const short8 bl = *(const short8*)(wl + kk * 32 + g * 8);
            acc = __builtin_amdgcn_mfma_f32_16x16x32_bf16(xf_h[kk], bh, acc, 0, 0, 0);
            acc = __builtin_amdgcn_mfma_f32_16x16x32_bf16(xf_l[kk], bh, acc, 0, 0, 0);
            acc = __builtin_amdgcn_mfma_f32_16x16x32_bf16(xf_h[kk], bl, acc, 0, 0, 0);
        }
        const float bias = b1[ncol];
#pragma unroll
        for (int r = 0; r < 4; ++r) {
            const int mm = 4 * g + r;
            const float hv = fmaxf(acc[r] + bias, 0.f);
            const ushort hh = f2bf(hv);
            Hh[mm * HSTR + ncol] = hh;
            Hl[mm * HSTR + ncol] = f2bf(hv - bf2f(hh));
        }
    }
    __syncthreads();

    const int obase = wave * 64;
    f32x4 acc2[4];
#pragma unroll
    for (int t = 0; t < 4; ++t) acc2[t] = (f32x4)(0.f);
#pragma unroll 2
    for (int kk = 0; kk < 16; ++kk) {
        const short8 ah = *(const short8*)&Hh[c16 * HSTR + kk * 32 + g * 8];
        const short8 al = *(const short8*)&Hl[c16 * HSTR + kk * 32 + g * 8];
#pragma unroll
        for (int t = 0; t < 4; ++t) {
            const int ncol = obase + t * 16 + c16;
            const short8 bh = *(const short8*)(w2th + (size_t)ncol * DFF + kk * 32 + g * 8);
            const short8 bl = *(const short8*)(w2tl + (size_t)ncol * DFF + kk * 32 + g * 8);
            acc2[t] = __builtin_amdgcn_mfma_f32_16x16x32_bf16(ah, bh, acc2[t], 0, 0, 0);
            acc2[t] = __builtin_amdgcn_mfma_f32_16x16x32_bf16(al, bh, acc2[t], 0, 0, 0);
            acc2[t] = __builtin_amdgcn_mfma_f32_16x16x32_bf16(ah, bl, acc2[t], 0, 0, 0);
        }
    }

#pragma unroll
    for (int t = 0; t < 4; ++t) {
        const int ncol = obase + t * 16 + c16;
#pragma unroll
        for (int r = 0; r < 4; ++r)
            Y[(4 * g + r) * YSTR + ncol] = acc2[t][r];
    }
    __syncthreads();

    const float g0 = gamma[0], b0 = beta[0];
#pragma unroll
    for (int rr = 0; rr < 4; ++rr) {
        const int row = wave * 4 + rr;
        float v[4];
        float sum = 0.f;
#pragma unroll
        for (int j = 0; j < 4; ++j) {
            const int c = lane + 64 * j;
            v[j] = Y[row * YSTR + c] + b2[c] + xin[(size_t)(row0 + row) * DD + c];
            sum += v[j];
        }
#pragma unroll
        for (int m = 32; m >= 1; m >>= 1) sum += __shfl_xor(sum, m);
        const float mean = sum * (1.0f / DD);
        float var = 0.f;
#pragma unroll
        for (int j = 0; j < 4; ++j) { v[j] -= mean; var += v[j] * v[j]; }
#pragma unroll
        for (int m = 32; m >= 1; m >>= 1) var += __shfl_xor(var, m);
        var *= (1.0f / DD);
        const float rstd = 1.0f / sqrtf(var + ln_eps2());
#pragma unroll
        for (int j = 0; j < 4; ++j)
            xout[(size_t)(row0 + row) * DD + lane + 64 * j] = v[j] * rstd * g0 + b0;
    }
}

// ---------------- host launch ----------------
extern "C" void kernel_launch(void* const* d_in, const int* in_sizes, int n_in,
                              void* d_out, int out_size, void* d_ws, size_t ws_size,
                              hipStream_t stream) {
    const float* x     = (const float*)d_in[0];
    const float* Wq    = (const float*)d_in[1];
    const float* Wk    = (const float*)d_in[2];
    const float* Wv    = (const float*)d_in[3];
    const float* Wo    = (const float*)d_in[4];
    const float* W1    = (const float*)d_in[5];
    const float* b1    = (const float*)d_in[6];
    const float* W2    = (const float*)d_in[7];
    const float* b2    = (const float*)d_in[8];
    const float* gamma = (const float*)d_in[9];
    const float* beta  = (const float*)d_in[10];
    float* out = (float*)d_out;

    const size_t NTOK = (size_t)BB * SS * DD;       // 1,048,576
    const size_t WFF  = (size_t)NL * DFF * DD;      // 262,144
    const size_t WOO  = (size_t)NL * DD * DD;       // 131,072
    const size_t WQKV = (size_t)NL * 768 * DD;      // 393,216
    float*  q    = (float*)d_ws;
    ushort* khi  = (ushort*)(q + NTOK);
    ushort* klo  = khi + NTOK;
    ushort* vt   = klo + NTOK;
    float*  o    = (float*)(vt + NTOK);
    float*  xa   = o + NTOK;
    float*  xb   = xa + NTOK;
    ushort* w1th = (ushort*)(xb + NTOK);
    ushort* w1tl = w1th + WFF;
    ushort* w2th = w1tl + WFF;
    ushort* w2tl = w2th + WFF;
    ushort* woth = w2tl + WFF;
    ushort* wotl = woth + WOO;
    ushort* wqth = wotl + WOO;
    ushort* wqtl = wqth + WQKV;
    float*  opart = (float*)(wqtl + WQKV);          // NSPLIT*B*H*S*DVV f32 = 16 MB
    float*  ml    = opart + (size_t)NSPLIT * BB * HH * SS * DVV;  // 1 MB

    wtrans_kernel<<<128, 256, 0, stream>>>(W1, W2, w1th, w1tl, w2th, w2tl);
    wotrans_kernel<<<NL * 16, 256, 0, stream>>>(Wo, woth, wotl);
    wqkv_trans_kernel<<<48, 256, 0, stream>>>(Wq, Wk, Wv, wqth, wqtl);

    const float* cur = x;
    for (int l = 0; l < NL; ++l) {
        qkv_mfma_kernel<<<2 * BB * SS / 16, 256, 0, stream>>>(
            cur, wqth + (size_t)l * 768 * DD, wqtl + (size_t)l * 768 * DD,
            q, khi, klo, vt);
        attn_mfma_kernel<<<BB * HH * (SS / 128) * NSPLIT, 256, 0, stream>>>(
            q, khi, klo, vt, opart, ml);
        attn_merge_kernel<<<BB * HH * (SS / 128), 256, 0, stream>>>(opart, ml, o);
        proj_mfma_kernel<<<BB * SS / 16, 256, 0, stream>>>(
            o, cur, woth + (size_t)l * DD * DD, wotl + (size_t)l * DD * DD,
            gamma + 2 * l, beta + 2 * l, xa);
        float* nxt = (l == NL - 1) ? out : xb;
        ffn_mfma_kernel<<<BB * SS / 16, 256, 0, stream>>>(
            xa, w1th + (size_t)l * DFF * DD, w1tl + (size_t)l * DFF * DD,
            w2th + (size_t)l * DD * DFF, w2tl + (size_t)l * DD * DFF,
            b1 + (size_t)l * DFF, b2 + (size_t)l * DD,
            gamma + 2 * l + 1, beta + 2 * l + 1, nxt);
        cur = nxt;
    }
}